// Round 5
// baseline (539.996 us; speedup 1.0000x reference)
//
#include <hip/hip_runtime.h>

typedef __bf16 bf16;
typedef __attribute__((ext_vector_type(8))) __bf16 bf16x8;
typedef __attribute__((ext_vector_type(4))) float f32x4;

typedef __attribute__((address_space(1))) void gvoid_t;
typedef __attribute__((address_space(3))) void lvoid_t;

#define LDS_LOAD16(gp, lp) \
    __builtin_amdgcn_global_load_lds((gvoid_t*)(gp), (lvoid_t*)(lp), 16, 0, 0)

// ---------------------------------------------------------------------------
// fp32 -> bf16 conversion, 8 elems/thread (two float4 loads, one 16B store).
// ---------------------------------------------------------------------------
__global__ __launch_bounds__(256)
void f32_to_bf16(const float* __restrict__ in, bf16* __restrict__ out, int n8)
{
    const int i = blockIdx.x * 256 + threadIdx.x;
    if (i >= n8) return;
    const float4 a = ((const float4*)in)[i * 2];
    const float4 b = ((const float4*)in)[i * 2 + 1];
    bf16x8 o;
    o[0] = (bf16)a.x; o[1] = (bf16)a.y; o[2] = (bf16)a.z; o[3] = (bf16)a.w;
    o[4] = (bf16)b.x; o[5] = (bf16)b.y; o[6] = (bf16)b.z; o[7] = (bf16)b.w;
    *(bf16x8*)(out + (size_t)i * 8) = o;
}

// ---------------------------------------------------------------------------
// Legacy 128x128 GEMM (kept for chunked-fallback QKV path).
// ---------------------------------------------------------------------------
template <int BIAS, typename CT>
__global__ __launch_bounds__(256, 2)
void gemm_bt(const bf16* __restrict__ A, const bf16* __restrict__ B,
             const float* __restrict__ bias, CT* __restrict__ C,
             int K, int ldc)
{
    __shared__ bf16 sA[128 * 32];
    __shared__ bf16 sB[128 * 32];
    const int tid  = threadIdx.x;
    const int lane = tid & 63;
    const int wid  = tid >> 6;
    const int m0 = blockIdx.y * 128;
    const int n0 = blockIdx.x * 128;
    const int wm = (wid >> 1) * 64;
    const int wn = (wid & 1) * 64;
    const int l15   = lane & 15;
    const int quad8 = (lane >> 4) * 8;

    f32x4 acc[4][4] = {};

    for (int k0 = 0; k0 < K; k0 += 32) {
#pragma unroll
        for (int t = 0; t < 2; ++t) {
            const int e  = (t * 4 + wid) * 512;
            const int ge = e + lane * 8;
            const int r = ge >> 5, c = ge & 31;
            LDS_LOAD16(A + (size_t)(m0 + r) * K + k0 + c, sA + e);
            LDS_LOAD16(B + (size_t)(n0 + r) * K + k0 + c, sB + e);
        }
        __syncthreads();

        bf16x8 af[4], bfr[4];
#pragma unroll
        for (int i = 0; i < 4; ++i) {
            af[i]  = *(const bf16x8*)(sA + (wm + i * 16 + l15) * 32 + quad8);
            bfr[i] = *(const bf16x8*)(sB + (wn + i * 16 + l15) * 32 + quad8);
        }
#pragma unroll
        for (int i = 0; i < 4; ++i)
#pragma unroll
            for (int j = 0; j < 4; ++j)
                acc[i][j] = __builtin_amdgcn_mfma_f32_16x16x32_bf16(af[i], bfr[j], acc[i][j], 0, 0, 0);
        __syncthreads();
    }

    const int rowBase = m0 + wm + (lane >> 4) * 4;
    const int colBase = n0 + wn + l15;
#pragma unroll
    for (int j = 0; j < 4; ++j) {
        const int col = colBase + j * 16;
        const float bv = BIAS ? bias[col] : 0.0f;
#pragma unroll
        for (int i = 0; i < 4; ++i) {
            const int row = rowBase + i * 16;
#pragma unroll
            for (int r = 0; r < 4; ++r)
                C[(size_t)(row + r) * ldc + col] = (CT)(acc[i][j][r] + bv);
        }
    }
}

// ---------------------------------------------------------------------------
// 128x192 GEMM v2: 4 waves (2Mx2N), per-wave 64x96 -> 0.417 LDS-reads/MFMA
//  (was 8 waves / 64x48 / 0.58: LDS-read-BW-bound at MfmaUtil 40%).
//  Per-wave reads now equal the wave's unique data (8 KiB A + 12 KiB B).
//  - 256 threads; BK=64; dbuf XOR-swizzled LDS = 80 KiB -> 2 blocks/CU
//    (8 waves/CU, 2/SIMD; co-resident block absorbs barrier drain).
//  - ONE barrier per K-tile; DMA for u+1 issued at tile start; counted
//    lgkm splits; setprio around MFMA clusters; vmcnt(0) at tile end.
//  - Swizzle both-sides: pre-swizzled global source + linear gload_lds dest
//    + XOR'd ds_read (colgroup ^= row&7) -> 0 bank conflicts (verified).
//  Requires M%128==0, N%192==0, K%64==0.
// ---------------------------------------------------------------------------
template <int BIAS, typename CT>
__global__ __launch_bounds__(256, 2)
void gemm128_bt(const bf16* __restrict__ A, const bf16* __restrict__ B,
                const float* __restrict__ bias, CT* __restrict__ C,
                int K, int ldc)
{
    __shared__ bf16 sA[2 * 128 * 64];   // 32 KiB, buf = 8192 elems (16384 B)
    __shared__ bf16 sB[2 * 192 * 64];   // 48 KiB, buf = 12288 elems (24576 B)

    const int tid  = threadIdx.x;
    const int lane = tid & 63;
    const int wid  = tid >> 6;              // 0..3
    const int m0 = blockIdx.y * 128;
    const int n0 = blockIdx.x * 192;
    const int wm = (wid >> 1) * 64;         // 0 / 64
    const int wn = (wid & 1) * 96;          // 0 / 96
    const int l15  = lane & 15;
    const int quad = lane >> 4;

    // staging offsets (source pre-swizzled, dest linear)
    int aoff[4], boff[6];
    int adst[4], bdst[6];
#pragma unroll
    for (int t = 0; t < 4; ++t) {
        const int slot = t * 256 + tid;       // A tile: 1024 slots of 8 elems
        const int r  = slot >> 3;             // row 0..127
        const int cg = (slot & 7) ^ (r & 7);
        aoff[t] = (m0 + r) * K + cg * 8;
        adst[t] = (t * 256 + wid * 64) * 8;   // wave-uniform LDS base (elems)
    }
#pragma unroll
    for (int t = 0; t < 6; ++t) {
        const int slot = t * 256 + tid;       // B tile: 1536 slots
        const int r  = slot >> 3;             // row 0..191
        const int cg = (slot & 7) ^ (r & 7);
        boff[t] = (n0 + r) * K + cg * 8;
        bdst[t] = (t * 256 + wid * 64) * 8;
    }

#define STA(t, kt, buf) LDS_LOAD16(A + (size_t)aoff[t] + (kt) * 64, sA + (buf) * 8192  + adst[t])
#define STB(t, kt, buf) LDS_LOAD16(B + (size_t)boff[t] + (kt) * 64, sB + (buf) * 12288 + bdst[t])

    // ds_read byte offsets per ksub (row&7 == l15&7 for all frag rows)
    int aRd[2], bRd[2];
#pragma unroll
    for (int kk = 0; kk < 2; ++kk) {
        const int pcg = (kk * 4 + quad) ^ (l15 & 7);
        aRd[kk] = (wm + l15) * 128 + pcg * 16;
        bRd[kk] = (wn + l15) * 128 + pcg * 16;
    }

    f32x4 acc[4][6] = {};

    // prologue: stage tile 0, retire fully.
#pragma unroll
    for (int t = 0; t < 4; ++t) STA(t, 0, 0);
#pragma unroll
    for (int t = 0; t < 6; ++t) STB(t, 0, 0);
    asm volatile("s_waitcnt vmcnt(0)" ::: "memory");

    const int NT = K >> 6;
#pragma unroll 1
    for (int u = 0; u < NT; ++u) {
        const int b = u & 1;
        __builtin_amdgcn_s_barrier();          // buf b complete for all waves
        if (u + 1 < NT) {                      // DMA overlaps this tile's compute
            STA(0, u + 1, b ^ 1); STA(1, u + 1, b ^ 1);
            STA(2, u + 1, b ^ 1); STA(3, u + 1, b ^ 1);
            STB(0, u + 1, b ^ 1); STB(1, u + 1, b ^ 1); STB(2, u + 1, b ^ 1);
            STB(3, u + 1, b ^ 1); STB(4, u + 1, b ^ 1); STB(5, u + 1, b ^ 1);
        }
        __builtin_amdgcn_sched_barrier(0);

        // group 1 reads: all A (8) + B nf0..2 (6) = 14 ds_read_b128
        bf16x8 af[4][2], bfr[6][2];
#pragma unroll
        for (int mi = 0; mi < 4; ++mi)
#pragma unroll
            for (int kk = 0; kk < 2; ++kk)
                af[mi][kk] = *(const bf16x8*)((const char*)sA + b * 16384 +
                                              aRd[kk] + mi * 2048);
#pragma unroll
        for (int nf = 0; nf < 3; ++nf)
#pragma unroll
            for (int kk = 0; kk < 2; ++kk)
                bfr[nf][kk] = *(const bf16x8*)((const char*)sB + b * 24576 +
                                               bRd[kk] + nf * 2048);
        __builtin_amdgcn_sched_barrier(0);     // pin issue order for lgkm(6)
        // group 2 reads: B nf3..5 (6)
#pragma unroll
        for (int nf = 3; nf < 6; ++nf)
#pragma unroll
            for (int kk = 0; kk < 2; ++kk)
                bfr[nf][kk] = *(const bf16x8*)((const char*)sB + b * 24576 +
                                               bRd[kk] + nf * 2048);
        __builtin_amdgcn_sched_barrier(0);

        asm volatile("s_waitcnt lgkmcnt(6)" ::: "memory");   // group 1 done
        __builtin_amdgcn_sched_barrier(0);
        __builtin_amdgcn_s_setprio(1);
#pragma unroll
        for (int mi = 0; mi < 4; ++mi)
#pragma unroll
            for (int nf = 0; nf < 3; ++nf)
#pragma unroll
                for (int kk = 0; kk < 2; ++kk)
                    acc[mi][nf] = __builtin_amdgcn_mfma_f32_16x16x32_bf16(
                        af[mi][kk], bfr[nf][kk], acc[mi][nf], 0, 0, 0);
        __builtin_amdgcn_sched_barrier(0);
        asm volatile("s_waitcnt lgkmcnt(0)" ::: "memory");   // group 2 done
        __builtin_amdgcn_sched_barrier(0);
#pragma unroll
        for (int mi = 0; mi < 4; ++mi)
#pragma unroll
            for (int nf = 3; nf < 6; ++nf)
#pragma unroll
                for (int kk = 0; kk < 2; ++kk)
                    acc[mi][nf] = __builtin_amdgcn_mfma_f32_16x16x32_bf16(
                        af[mi][kk], bfr[nf][kk], acc[mi][nf], 0, 0, 0);
        __builtin_amdgcn_s_setprio(0);
        __builtin_amdgcn_sched_barrier(0);
        asm volatile("s_waitcnt vmcnt(0)" ::: "memory");     // tile u+1 DMA done
    }
#undef STA
#undef STB

    const int rowBase = m0 + wm + quad * 4;
    const int colBase = n0 + wn + l15;
#pragma unroll
    for (int nf = 0; nf < 6; ++nf) {
        const int col = colBase + nf * 16;
        const float bv = BIAS ? bias[col] : 0.0f;
#pragma unroll
        for (int mf = 0; mf < 4; ++mf) {
            const int row = rowBase + mf * 16;
#pragma unroll
            for (int r = 0; r < 4; ++r)
                C[(size_t)(row + r) * ldc + col] = (CT)(acc[mf][nf][r] + bv);
        }
    }
}

// ---------------------------------------------------------------------------
// 64x192 proj GEMM v2: 4 waves (1Mx4N), per-wave 64x48 -> 0.58 reads/MFMA
//  (was 8 waves / 32x48 / 0.83). 256 threads, LDS 64 KiB -> 2 blocks/CU.
//  Grid 16x32 = 512 blocks = exactly 2/CU, balanced. Same schedule as v2.
//  Requires M%64==0, N%192==0, K%64==0.
// ---------------------------------------------------------------------------
template <int BIAS, typename CT>
__global__ __launch_bounds__(256, 2)
void gemm64_bt(const bf16* __restrict__ A, const bf16* __restrict__ B,
               const float* __restrict__ bias, CT* __restrict__ C,
               int K, int ldc)
{
    __shared__ bf16 sA[2 * 64 * 64];    // 16 KiB, buf = 4096 elems
    __shared__ bf16 sB[2 * 192 * 64];   // 48 KiB, buf = 12288 elems

    const int tid  = threadIdx.x;
    const int lane = tid & 63;
    const int wid  = tid >> 6;              // 0..3
    const int m0 = blockIdx.y * 64;
    const int n0 = blockIdx.x * 192;
    const int wn = wid * 48;                // 0/48/96/144
    const int l15  = lane & 15;
    const int quad = lane >> 4;

    int aoff[2], adst[2], boff[6], bdst[6];
#pragma unroll
    for (int t = 0; t < 2; ++t) {
        const int slot = t * 256 + tid;       // A tile: 512 slots
        const int r  = slot >> 3;             // row 0..63
        const int cg = (slot & 7) ^ (r & 7);
        aoff[t] = (m0 + r) * K + cg * 8;
        adst[t] = (t * 256 + wid * 64) * 8;
    }
#pragma unroll
    for (int t = 0; t < 6; ++t) {
        const int slot = t * 256 + tid;       // B tile: 1536 slots
        const int r  = slot >> 3;
        const int cg = (slot & 7) ^ (r & 7);
        boff[t] = (n0 + r) * K + cg * 8;
        bdst[t] = (t * 256 + wid * 64) * 8;
    }

#define STA64(t, kt, buf) LDS_LOAD16(A + (size_t)aoff[t] + (kt) * 64, sA + (buf) * 4096  + adst[t])
#define STB64(t, kt, buf) LDS_LOAD16(B + (size_t)boff[t] + (kt) * 64, sB + (buf) * 12288 + bdst[t])

    int aRd[2], bRd[2];
#pragma unroll
    for (int kk = 0; kk < 2; ++kk) {
        const int pcg = (kk * 4 + quad) ^ (l15 & 7);
        aRd[kk] = l15 * 128 + pcg * 16;               // wm = 0
        bRd[kk] = (wn + l15) * 128 + pcg * 16;
    }

    f32x4 acc[4][3] = {};

#pragma unroll
    for (int t = 0; t < 2; ++t) STA64(t, 0, 0);
#pragma unroll
    for (int t = 0; t < 6; ++t) STB64(t, 0, 0);
    asm volatile("s_waitcnt vmcnt(0)" ::: "memory");

    const int NT = K >> 6;
#pragma unroll 1
    for (int u = 0; u < NT; ++u) {
        const int b = u & 1;
        __builtin_amdgcn_s_barrier();
        if (u + 1 < NT) {
            STA64(0, u + 1, b ^ 1); STA64(1, u + 1, b ^ 1);
            STB64(0, u + 1, b ^ 1); STB64(1, u + 1, b ^ 1); STB64(2, u + 1, b ^ 1);
            STB64(3, u + 1, b ^ 1); STB64(4, u + 1, b ^ 1); STB64(5, u + 1, b ^ 1);
        }
        __builtin_amdgcn_sched_barrier(0);

        // group 1 reads: all A (8) + B nf0..1 (4) = 12
        bf16x8 af[4][2], bfr[3][2];
#pragma unroll
        for (int mi = 0; mi < 4; ++mi)
#pragma unroll
            for (int kk = 0; kk < 2; ++kk)
                af[mi][kk] = *(const bf16x8*)((const char*)sA + b * 8192 +
                                              aRd[kk] + mi * 2048);
#pragma unroll
        for (int nf = 0; nf < 2; ++nf)
#pragma unroll
            for (int kk = 0; kk < 2; ++kk)
                bfr[nf][kk] = *(const bf16x8*)((const char*)sB + b * 24576 +
                                               bRd[kk] + nf * 2048);
        __builtin_amdgcn_sched_barrier(0);     // pin issue order for lgkm(2)
        // group 2 reads: B nf2 (2)
#pragma unroll
        for (int kk = 0; kk < 2; ++kk)
            bfr[2][kk] = *(const bf16x8*)((const char*)sB + b * 24576 +
                                          bRd[kk] + 2 * 2048);
        __builtin_amdgcn_sched_barrier(0);

        asm volatile("s_waitcnt lgkmcnt(2)" ::: "memory");   // group 1 done
        __builtin_amdgcn_sched_barrier(0);
        __builtin_amdgcn_s_setprio(1);
#pragma unroll
        for (int mi = 0; mi < 4; ++mi)
#pragma unroll
            for (int nf = 0; nf < 2; ++nf)
#pragma unroll
                for (int kk = 0; kk < 2; ++kk)
                    acc[mi][nf] = __builtin_amdgcn_mfma_f32_16x16x32_bf16(
                        af[mi][kk], bfr[nf][kk], acc[mi][nf], 0, 0, 0);
        __builtin_amdgcn_sched_barrier(0);
        asm volatile("s_waitcnt lgkmcnt(0)" ::: "memory");   // group 2 done
        __builtin_amdgcn_sched_barrier(0);
#pragma unroll
        for (int mi = 0; mi < 4; ++mi)
#pragma unroll
            for (int kk = 0; kk < 2; ++kk)
                acc[mi][2] = __builtin_amdgcn_mfma_f32_16x16x32_bf16(
                    af[mi][kk], bfr[2][kk], acc[mi][2], 0, 0, 0);
        __builtin_amdgcn_s_setprio(0);
        __builtin_amdgcn_sched_barrier(0);
        asm volatile("s_waitcnt vmcnt(0)" ::: "memory");
    }
#undef STA64
#undef STB64

    const int rowBase = m0 + quad * 4;
    const int colBase = n0 + wn + l15;
#pragma unroll
    for (int nf = 0; nf < 3; ++nf) {
        const int col = colBase + nf * 16;
        const float bv = BIAS ? bias[col] : 0.0f;
#pragma unroll
        for (int mf = 0; mf < 4; ++mf) {
            const int row = rowBase + mf * 16;
#pragma unroll
            for (int r = 0; r < 4; ++r)
                C[(size_t)(row + r) * ldc + col] = (CT)(acc[mf][nf][r] + bv);
        }
    }
}

// ---------------------------------------------------------------------------
// QKNorm (fp32 RMS over head_dim=128) + RoPE + rearrange.
//  qkv [L][9216] bf16 -> Qh/Kh [24][2048][128] (normed+roped), Vt [24][128][2048].
// ---------------------------------------------------------------------------
__global__ __launch_bounds__(256)
void qk_rope_rearrange(const bf16* __restrict__ qkv, const float* __restrict__ pe,
                       const float* __restrict__ qs, const float* __restrict__ ks,
                       bf16* __restrict__ Qh, bf16* __restrict__ Kh, bf16* __restrict__ Vt)
{
    const int lane = threadIdx.x & 63;
    const int wid  = threadIdx.x >> 6;
    const int idx  = blockIdx.x * 4 + wid;     // = h*2048 + l
    const int h = idx >> 11;
    const int l = idx & 2047;

    const size_t rowb = (size_t)l * 9216 + h * 128 + 2 * lane;
    const float q0 = (float)qkv[rowb];
    const float q1 = (float)qkv[rowb + 1];
    const float k0 = (float)qkv[rowb + 3072];
    const float k1 = (float)qkv[rowb + 3073];
    const bf16  v0 = qkv[rowb + 6144];
    const bf16  v1 = qkv[rowb + 6145];

    float ssq = q0 * q0 + q1 * q1;
    float ssk = k0 * k0 + k1 * k1;
#pragma unroll
    for (int off = 1; off < 64; off <<= 1) {
        ssq += __shfl_xor(ssq, off);
        ssk += __shfl_xor(ssk, off);
    }
    const float rq = rsqrtf(ssq * (1.0f / 128.0f) + 1e-6f);
    const float rk = rsqrtf(ssk * (1.0f / 128.0f) + 1e-6f);

    const float s0q = qs[2 * lane], s1q = qs[2 * lane + 1];
    const float s0k = ks[2 * lane], s1k = ks[2 * lane + 1];

    const float qn0 = (q0 * rq) * s0q;
    const float qn1 = (q1 * rq) * s1q;
    const float kn0 = (k0 * rk) * s0k;
    const float kn1 = (k1 * rk) * s1k;

    const float* pp = pe + ((size_t)l * 64 + lane) * 4;
    const float p00 = pp[0], p01 = pp[1];
    const float p10 = pp[2], p11 = pp[3];

    const bf16 qo0 = (bf16)(p00 * qn0 + p01 * qn1);
    const bf16 qo1 = (bf16)(p10 * qn0 + p11 * qn1);
    const bf16 ko0 = (bf16)(p00 * kn0 + p01 * kn1);
    const bf16 ko1 = (bf16)(p10 * kn0 + p11 * kn1);

    const size_t ob = ((size_t)h * 2048 + l) * 128 + 2 * lane;
    Qh[ob] = qo0; Qh[ob + 1] = qo1;
    Kh[ob] = ko0; Kh[ob + 1] = ko1;

    const size_t vb = ((size_t)h * 128 + 2 * lane) * 2048 + l;
    Vt[vb]        = v0;
    Vt[vb + 2048] = v1;
}

// ---------------------------------------------------------------------------
// Flash attention v3. Block = 4 waves x 16 q-rows = 64 q; kv-steps of 64.
//  - K AND V staged via async global_load_lds into XOR-swizzled LDS tiles;
//    both double-buffered -> ONE barrier per step; DMA overlaps compute.
//  - No-max softmax: p = exp(s/sqrt(d)); row-sum via 2 MFMAs vs ones.
//  - setprio(1) wraps the MFMA clusters (T5: attn-proven +4-7%, m191).
// ---------------------------------------------------------------------------
__global__ __launch_bounds__(256, 2)
void flash_attn(const bf16* __restrict__ Qh, const bf16* __restrict__ Kh,
                const bf16* __restrict__ Vt, bf16* __restrict__ AO)
{
    __shared__ bf16 sK[2 * 64 * 128];  // [kv][d] swizzled, dbuf, 32 KB
    __shared__ bf16 sV[2 * 128 * 64];  // [d][kv] swizzled, dbuf, 32 KB
    __shared__ bf16 sP[4 * 16 * 72];   // per-wave P [q][kv], stride 72

    const int tid   = threadIdx.x;
    const int lane  = tid & 63;
    const int wid   = tid >> 6;
    const int h     = blockIdx.y;
    const int qw    = blockIdx.x * 64 + wid * 16;
    const int l15   = lane & 15;
    const int quad  = lane >> 4;
    const int quad8 = quad * 8;

    const bf16* Kbase = Kh + (size_t)h * 2048 * 128;
    const bf16* Vbase = Vt + (size_t)h * 128 * 2048;

    bf16x8 aq[4];
    {
        const bf16* qp = Qh + ((size_t)h * 2048 + qw + l15) * 128 + quad8;
#pragma unroll
        for (int ki = 0; ki < 4; ++ki) aq[ki] = *(const bf16x8*)(qp + ki * 32);
    }

    bf16x8 ones;
#pragma unroll
    for (int i = 0; i < 8; ++i) ones[i] = (bf16)1.0f;

    f32x4 o[8] = {};
    f32x4 lacc = {};

    bf16* sPw = sP + wid * (16 * 72);
    const int slotbase = wid * 64;

#define STAGE_K(kv, buf)                                                         \
    {                                                                            \
        bf16* kb = sK + (buf) * (64 * 128);                                      \
        _Pragma("unroll")                                                        \
        for (int t = 0; t < 4; ++t) {                                            \
            const int sb   = t * 256 + slotbase;                                 \
            const int slot = sb + lane;                                          \
            const int r    = slot >> 4;                                          \
            const int cg   = (slot & 15) ^ (r & 7);                              \
            LDS_LOAD16(Kbase + (size_t)((kv) + r) * 128 + cg * 8, kb + sb * 8);  \
        }                                                                        \
    }
#define STAGE_V(kv, buf)                                                         \
    {                                                                            \
        bf16* vb = sV + (buf) * (128 * 64);                                      \
        _Pragma("unroll")                                                        \
        for (int t = 0; t < 4; ++t) {                                            \
            const int sb   = t * 256 + slotbase;                                 \
            const int slot = sb + lane;                                          \
            const int r    = slot >> 3;                                          \
            const int cg   = (slot & 7) ^ (r & 7);                               \
            LDS_LOAD16(Vbase + (size_t)r * 2048 + (kv) + cg * 8, vb + sb * 8);   \
        }                                                                        \
    }

    STAGE_K(0, 0);
    STAGE_V(0, 0);

    for (int s = 0; s < 32; ++s) {
        __syncthreads();
        if (s < 31) {
            STAGE_K((s + 1) * 64, (s + 1) & 1);
            STAGE_V((s + 1) * 64, (s + 1) & 1);
        }

        const bf16* kb = sK + (s & 1) * (64 * 128);
        const bf16* vb = sV + (s & 1) * (128 * 64);

        // S = Q K^T  (16 MFMA), swizzled sK reads
        f32x4 sc[4];
        __builtin_amdgcn_s_setprio(1);
#pragma unroll
        for (int nt = 0; nt < 4; ++nt) {
            f32x4 t = {};
            const int row = nt * 16 + l15;
#pragma unroll
            for (int ki = 0; ki < 4; ++ki) {
                const int pcg = (4 * ki + quad) ^ (l15 & 7);
                bf16x8 bk = *(const bf16x8*)(kb + row * 128 + pcg * 8);
                t = __builtin_amdgcn_mfma_f32_16x16x32_bf16(aq[ki], bk, t, 0, 0, 0);
            }
            sc[nt] = t;
        }
        __builtin_amdgcn_s_setprio(0);

        // p = exp(s * scale); write P to LDS (C-layout -> A-layout transform)
#pragma unroll
        for (int r = 0; r < 4; ++r) {
            const float scl = 0.08838834764831845f;   // 1/sqrt(128)
            bf16* pw = sPw + (quad * 4 + r) * 72 + l15;
            pw[0]  = (bf16)__expf(sc[0][r] * scl);
            pw[16] = (bf16)__expf(sc[1][r] * scl);
            pw[32] = (bf16)__expf(sc[2][r] * scl);
            pw[48] = (bf16)__expf(sc[3][r] * scl);
        }

        // PV (16 MFMA, V from swizzled sV) + row-sum l (2 MFMA vs ones)
        __builtin_amdgcn_s_setprio(1);
#pragma unroll
        for (int kk = 0; kk < 2; ++kk) {
            bf16x8 pa = *(const bf16x8*)(sPw + l15 * 72 + kk * 32 + quad8);
            lacc = __builtin_amdgcn_mfma_f32_16x16x32_bf16(pa, ones, lacc, 0, 0, 0);
#pragma unroll
            for (int dt = 0; dt < 8; ++dt) {
                const int row = dt * 16 + l15;
                const int pcg = (kk * 4 + quad) ^ (l15 & 7);
                bf16x8 bv = *(const bf16x8*)(vb + row * 64 + pcg * 8);
                o[dt] = __builtin_amdgcn_mfma_f32_16x16x32_bf16(pa, bv, o[dt], 0, 0, 0);
            }
        }
        __builtin_amdgcn_s_setprio(0);
    }
#undef STAGE_K
#undef STAGE_V

#pragma unroll
    for (int r = 0; r < 4; ++r) {
        const float inv = 1.0f / lacc[r];
        const size_t row = qw + quad * 4 + r;
        bf16* op = AO + row * 3072 + h * 128 + l15;
#pragma unroll
        for (int dt = 0; dt < 8; ++dt) op[dt * 16] = (bf16)(o[dt][r] * inv);
    }
}

// ---------------------------------------------------------------------------
extern "C" void kernel_launch(void* const* d_in, const int* in_sizes, int n_in,
                              void* d_out, int out_size, void* d_ws, size_t ws_size,
                              hipStream_t stream)
{
    (void)in_sizes; (void)n_in; (void)out_size;

    const float* x      = (const float*)d_in[0];
    const float* pe     = (const float*)d_in[1];
    const float* w_qkv  = (const float*)d_in[2];
    const float* w_proj = (const float*)d_in[3];
    const float* b_proj = (const float*)d_in[4];
    const float* q_s    = (const float*)d_in[5];
    const float* k_s    = (const float*)d_in[6];
    float* out = (float*)d_out;

    const size_t NEED_BIG = ((size_t)6291456 + 28311552 + 18874368 + 6291456) * 2; // 119.5 MB

    if (ws_size >= NEED_BIG) {
        // single-launch QKV path
        bf16* xb  = (bf16*)d_ws;                  //  6291456  x bf16
        bf16* wb  = xb + (size_t)6291456;         // 28311552  w_qkv bf16
        bf16* qkv = wb + (size_t)28311552;        // 18874368  [2048][9216]
        bf16* Vt  = qkv + (size_t)18874368;       //  6291456  [24][128][2048]
        bf16* Qh  = xb;                           // alias after GEMM
        bf16* Kh  = wb;                           // alias after GEMM
        bf16* wpb = qkv;                          // alias after rearrange
        bf16* AO  = qkv + (size_t)9437184;

        f32_to_bf16<<<dim3(3072),  256, 0, stream>>>(x,     xb, 786432);
        f32_to_bf16<<<dim3(13824), 256, 0, stream>>>(w_qkv, wb, 3538944);
        // 128x192 GEMM v2 (4-wave): grid 48x16 = 768 blocks @ 2/CU
        gemm128_bt<0, bf16><<<dim3(48, 16), 256, 0, stream>>>(xb, wb, nullptr, qkv, 3072, 9216);
        qk_rope_rearrange<<<dim3(12288), 256, 0, stream>>>(qkv, pe, q_s, k_s, Qh, Kh, Vt);
        f32_to_bf16<<<dim3(4608), 256, 0, stream>>>(w_proj, wpb, 1179648);
        flash_attn<<<dim3(32, 24), 256, 0, stream>>>(Qh, Kh, Vt, AO);
        // 64x192 proj GEMM v2 (4-wave): grid 16x32 = 512 blocks = exactly 2/CU
        gemm64_bt<1, float><<<dim3(16, 32), 256, 0, stream>>>(AO, wpb, b_proj, out, 3072, 3072);
    } else {
        // chunked fallback (78.6 MB peak)
        bf16* xb  = (bf16*)d_ws;
        bf16* wb  = xb + (size_t)6291456;
        bf16* qkv = wb + (size_t)9437184;
        bf16* Vt  = qkv + (size_t)18874368;
        bf16* Qh  = xb;
        bf16* Kh  = wb;
        bf16* wpb = qkv;
        bf16* AO  = qkv + (size_t)9437184;

        f32_to_bf16<<<dim3(3072), 256, 0, stream>>>(x, xb, 786432);
        for (int c = 0; c < 3; ++c) {
            f32_to_bf16<<<dim3(4608), 256, 0, stream>>>(w_qkv + (size_t)c * 9437184, wb, 1179648);
            gemm_bt<0, bf16><<<dim3(24, 16), 256, 0, stream>>>(xb, wb, nullptr, qkv + c * 3072, 3072, 9216);
        }
        qk_rope_rearrange<<<dim3(12288), 256, 0, stream>>>(qkv, pe, q_s, k_s, Qh, Kh, Vt);
        f32_to_bf16<<<dim3(4608), 256, 0, stream>>>(w_proj, wpb, 1179648);
        flash_attn<<<dim3(32, 24), 256, 0, stream>>>(Qh, Kh, Vt, AO);
        gemm64_bt<1, float><<<dim3(16, 32), 256, 0, stream>>>(AO, wpb, b_proj, out, 3072, 3072);
    }
}

// Round 6
// 530.044 us; speedup vs baseline: 1.0188x; 1.0188x over previous
//
#include <hip/hip_runtime.h>

typedef __bf16 bf16;
typedef __attribute__((ext_vector_type(4))) __bf16 bf16x4;
typedef __attribute__((ext_vector_type(8))) __bf16 bf16x8;
typedef __attribute__((ext_vector_type(4))) float f32x4;

typedef __attribute__((address_space(1))) void gvoid_t;
typedef __attribute__((address_space(3))) void lvoid_t;

#define LDS_LOAD16(gp, lp) \
    __builtin_amdgcn_global_load_lds((gvoid_t*)(gp), (lvoid_t*)(lp), 16, 0, 0)

// ---------------------------------------------------------------------------
// fp32 -> bf16 conversion, 8 elems/thread (two float4 loads, one 16B store).
// ---------------------------------------------------------------------------
__global__ __launch_bounds__(256)
void f32_to_bf16(const float* __restrict__ in, bf16* __restrict__ out, int n8)
{
    const int i = blockIdx.x * 256 + threadIdx.x;
    if (i >= n8) return;
    const float4 a = ((const float4*)in)[i * 2];
    const float4 b = ((const float4*)in)[i * 2 + 1];
    bf16x8 o;
    o[0] = (bf16)a.x; o[1] = (bf16)a.y; o[2] = (bf16)a.z; o[3] = (bf16)a.w;
    o[4] = (bf16)b.x; o[5] = (bf16)b.y; o[6] = (bf16)b.z; o[7] = (bf16)b.w;
    *(bf16x8*)(out + (size_t)i * 8) = o;
}

// ---------------------------------------------------------------------------
// Legacy 128x128 GEMM (kept for chunked-fallback QKV path).
// ---------------------------------------------------------------------------
template <int BIAS, typename CT>
__global__ __launch_bounds__(256, 2)
void gemm_bt(const bf16* __restrict__ A, const bf16* __restrict__ B,
             const float* __restrict__ bias, CT* __restrict__ C,
             int K, int ldc)
{
    __shared__ bf16 sA[128 * 32];
    __shared__ bf16 sB[128 * 32];
    const int tid  = threadIdx.x;
    const int lane = tid & 63;
    const int wid  = tid >> 6;
    const int m0 = blockIdx.y * 128;
    const int n0 = blockIdx.x * 128;
    const int wm = (wid >> 1) * 64;
    const int wn = (wid & 1) * 64;
    const int l15   = lane & 15;
    const int quad8 = (lane >> 4) * 8;

    f32x4 acc[4][4] = {};

    for (int k0 = 0; k0 < K; k0 += 32) {
#pragma unroll
        for (int t = 0; t < 2; ++t) {
            const int e  = (t * 4 + wid) * 512;
            const int ge = e + lane * 8;
            const int r = ge >> 5, c = ge & 31;
            LDS_LOAD16(A + (size_t)(m0 + r) * K + k0 + c, sA + e);
            LDS_LOAD16(B + (size_t)(n0 + r) * K + k0 + c, sB + e);
        }
        __syncthreads();

        bf16x8 af[4], bfr[4];
#pragma unroll
        for (int i = 0; i < 4; ++i) {
            af[i]  = *(const bf16x8*)(sA + (wm + i * 16 + l15) * 32 + quad8);
            bfr[i] = *(const bf16x8*)(sB + (wn + i * 16 + l15) * 32 + quad8);
        }
#pragma unroll
        for (int i = 0; i < 4; ++i)
#pragma unroll
            for (int j = 0; j < 4; ++j)
                acc[i][j] = __builtin_amdgcn_mfma_f32_16x16x32_bf16(af[i], bfr[j], acc[i][j], 0, 0, 0);
        __syncthreads();
    }

    const int rowBase = m0 + wm + (lane >> 4) * 4;
    const int colBase = n0 + wn + l15;
#pragma unroll
    for (int j = 0; j < 4; ++j) {
        const int col = colBase + j * 16;
        const float bv = BIAS ? bias[col] : 0.0f;
#pragma unroll
        for (int i = 0; i < 4; ++i) {
            const int row = rowBase + i * 16;
#pragma unroll
            for (int r = 0; r < 4; ++r)
                C[(size_t)(row + r) * ldc + col] = (CT)(acc[i][j][r] + bv);
        }
    }
}

// ---------------------------------------------------------------------------
// 128x192 GEMM @ 2 blocks/CU (round-3 proven: 124 us on QKV shape, 932 TF).
//  8 waves (2Mx4N), per-wave 64x48. BK=64, dbuf XOR-swizzled LDS = 80 KiB.
//  16 waves/CU: co-resident block absorbs barrier/vmcnt idle (round-3 win;
//  round-4's 4-wave variant regressed -> TLP dominates per-wave efficiency).
// ---------------------------------------------------------------------------
template <int BIAS, typename CT>
__global__ __launch_bounds__(512, 4)
void gemm128_bt(const bf16* __restrict__ A, const bf16* __restrict__ B,
                const float* __restrict__ bias, CT* __restrict__ C,
                int K, int ldc)
{
    __shared__ bf16 sA[2 * 128 * 64];   // 32 KiB
    __shared__ bf16 sB[2 * 192 * 64];   // 48 KiB

    const int tid  = threadIdx.x;
    const int lane = tid & 63;
    const int wid  = tid >> 6;
    const int m0 = blockIdx.y * 128;
    const int n0 = blockIdx.x * 192;
    const int wm = (wid >> 2) * 64;
    const int wn = (wid & 3) * 48;
    const int l15  = lane & 15;
    const int quad = lane >> 4;

    int aoff[2], boff[3];
    int adst[2], bdst[3];
#pragma unroll
    for (int t = 0; t < 2; ++t) {
        const int slot = t * 512 + tid;
        const int r  = slot >> 3;
        const int cg = (slot & 7) ^ (r & 7);
        aoff[t] = (m0 + r) * K + cg * 8;
        adst[t] = (t * 512 + wid * 64) * 8;
    }
#pragma unroll
    for (int t = 0; t < 3; ++t) {
        const int slot = t * 512 + tid;
        const int r  = slot >> 3;
        const int cg = (slot & 7) ^ (r & 7);
        boff[t] = (n0 + r) * K + cg * 8;
        bdst[t] = (t * 512 + wid * 64) * 8;
    }

#define STA(t, kt, buf) LDS_LOAD16(A + (size_t)aoff[t] + (kt) * 64, sA + (buf) * 8192  + adst[t])
#define STB(t, kt, buf) LDS_LOAD16(B + (size_t)boff[t] + (kt) * 64, sB + (buf) * 12288 + bdst[t])

    int aRd[2], bRd[2];
#pragma unroll
    for (int kk = 0; kk < 2; ++kk) {
        const int pcg = (kk * 4 + quad) ^ (l15 & 7);
        aRd[kk] = (wm + l15) * 128 + pcg * 16;
        bRd[kk] = (wn + l15) * 128 + pcg * 16;
    }

    f32x4 acc[4][3] = {};

#pragma unroll
    for (int t = 0; t < 2; ++t) STA(t, 0, 0);
#pragma unroll
    for (int t = 0; t < 3; ++t) STB(t, 0, 0);
    asm volatile("s_waitcnt vmcnt(0)" ::: "memory");

    const int NT = K >> 6;
#pragma unroll 1
    for (int u = 0; u < NT; ++u) {
        const int b = u & 1;
        __builtin_amdgcn_s_barrier();
        if (u + 1 < NT) {
            STA(0, u + 1, b ^ 1); STA(1, u + 1, b ^ 1);
            STB(0, u + 1, b ^ 1); STB(1, u + 1, b ^ 1); STB(2, u + 1, b ^ 1);
        }
        __builtin_amdgcn_sched_barrier(0);

        bf16x8 af[4][2], bfr[3][2];
#pragma unroll
        for (int mi = 0; mi < 2; ++mi)
#pragma unroll
            for (int kk = 0; kk < 2; ++kk)
                af[mi][kk] = *(const bf16x8*)((const char*)sA + b * 16384 +
                                              aRd[kk] + mi * 2048);
#pragma unroll
        for (int nf = 0; nf < 3; ++nf)
#pragma unroll
            for (int kk = 0; kk < 2; ++kk)
                bfr[nf][kk] = *(const bf16x8*)((const char*)sB + b * 24576 +
                                               bRd[kk] + nf * 2048);
        __builtin_amdgcn_sched_barrier(0);
#pragma unroll
        for (int mi = 2; mi < 4; ++mi)
#pragma unroll
            for (int kk = 0; kk < 2; ++kk)
                af[mi][kk] = *(const bf16x8*)((const char*)sA + b * 16384 +
                                              aRd[kk] + mi * 2048);
        __builtin_amdgcn_sched_barrier(0);

        asm volatile("s_waitcnt lgkmcnt(4)" ::: "memory");
        __builtin_amdgcn_sched_barrier(0);
        __builtin_amdgcn_s_setprio(1);
#pragma unroll
        for (int mi = 0; mi < 2; ++mi)
#pragma unroll
            for (int nf = 0; nf < 3; ++nf)
#pragma unroll
                for (int kk = 0; kk < 2; ++kk)
                    acc[mi][nf] = __builtin_amdgcn_mfma_f32_16x16x32_bf16(
                        af[mi][kk], bfr[nf][kk], acc[mi][nf], 0, 0, 0);
        __builtin_amdgcn_sched_barrier(0);
        asm volatile("s_waitcnt lgkmcnt(0)" ::: "memory");
        __builtin_amdgcn_sched_barrier(0);
#pragma unroll
        for (int mi = 2; mi < 4; ++mi)
#pragma unroll
            for (int nf = 0; nf < 3; ++nf)
#pragma unroll
                for (int kk = 0; kk < 2; ++kk)
                    acc[mi][nf] = __builtin_amdgcn_mfma_f32_16x16x32_bf16(
                        af[mi][kk], bfr[nf][kk], acc[mi][nf], 0, 0, 0);
        __builtin_amdgcn_s_setprio(0);
        __builtin_amdgcn_sched_barrier(0);
        asm volatile("s_waitcnt vmcnt(0)" ::: "memory");
    }
#undef STA
#undef STB

    const int rowBase = m0 + wm + quad * 4;
    const int colBase = n0 + wn + l15;
#pragma unroll
    for (int nf = 0; nf < 3; ++nf) {
        const int col = colBase + nf * 16;
        const float bv = BIAS ? bias[col] : 0.0f;
#pragma unroll
        for (int mf = 0; mf < 4; ++mf) {
            const int row = rowBase + mf * 16;
#pragma unroll
            for (int r = 0; r < 4; ++r)
                C[(size_t)(row + r) * ldc + col] = (CT)(acc[mf][nf][r] + bv);
        }
    }
}

// ---------------------------------------------------------------------------
// 64x192 proj GEMM @ 2 blocks/CU (round-3 proven). 8 waves = 2M x 4N;
//  per-wave 32x48. LDS 64 KiB. Grid 16x32 = 512 blocks = exactly 2/CU.
// ---------------------------------------------------------------------------
template <int BIAS, typename CT>
__global__ __launch_bounds__(512, 4)
void gemm64_bt(const bf16* __restrict__ A, const bf16* __restrict__ B,
               const float* __restrict__ bias, CT* __restrict__ C,
               int K, int ldc)
{
    __shared__ bf16 sA[2 * 64 * 64];    // 16 KiB
    __shared__ bf16 sB[2 * 192 * 64];   // 48 KiB

    const int tid  = threadIdx.x;
    const int lane = tid & 63;
    const int wid  = tid >> 6;
    const int m0 = blockIdx.y * 64;
    const int n0 = blockIdx.x * 192;
    const int wm = (wid >> 2) * 32;
    const int wn = (wid & 3) * 48;
    const int l15  = lane & 15;
    const int quad = lane >> 4;

    int aoff, adst;
    {
        const int slot = tid;
        const int r  = slot >> 3;
        const int cg = (slot & 7) ^ (r & 7);
        aoff = (m0 + r) * K + cg * 8;
        adst = (wid * 64) * 8;
    }
    int boff[3], bdst[3];
#pragma unroll
    for (int t = 0; t < 3; ++t) {
        const int slot = t * 512 + tid;
        const int r  = slot >> 3;
        const int cg = (slot & 7) ^ (r & 7);
        boff[t] = (n0 + r) * K + cg * 8;
        bdst[t] = (t * 512 + wid * 64) * 8;
    }

#define STA64(kt, buf)    LDS_LOAD16(A + (size_t)aoff    + (kt) * 64, sA + (buf) * 4096  + adst)
#define STB64(t, kt, buf) LDS_LOAD16(B + (size_t)boff[t] + (kt) * 64, sB + (buf) * 12288 + bdst[t])

    int aRd[2], bRd[2];
#pragma unroll
    for (int kk = 0; kk < 2; ++kk) {
        const int pcg = (kk * 4 + quad) ^ (l15 & 7);
        aRd[kk] = (wm + l15) * 128 + pcg * 16;
        bRd[kk] = (wn + l15) * 128 + pcg * 16;
    }

    f32x4 acc[2][3] = {};

    STA64(0, 0);
#pragma unroll
    for (int t = 0; t < 3; ++t) STB64(t, 0, 0);
    asm volatile("s_waitcnt vmcnt(0)" ::: "memory");

    const int NT = K >> 6;
#pragma unroll 1
    for (int u = 0; u < NT; ++u) {
        const int b = u & 1;
        __builtin_amdgcn_s_barrier();
        if (u + 1 < NT) {
            STA64(u + 1, b ^ 1);
            STB64(0, u + 1, b ^ 1); STB64(1, u + 1, b ^ 1); STB64(2, u + 1, b ^ 1);
        }
        __builtin_amdgcn_sched_barrier(0);

        bf16x8 af[2][2], bfr[3][2];
#pragma unroll
        for (int kk = 0; kk < 2; ++kk)
            af[0][kk] = *(const bf16x8*)((const char*)sA + b * 8192 + aRd[kk]);
#pragma unroll
        for (int nf = 0; nf < 3; ++nf)
#pragma unroll
            for (int kk = 0; kk < 2; ++kk)
                bfr[nf][kk] = *(const bf16x8*)((const char*)sB + b * 24576 +
                                               bRd[kk] + nf * 2048);
        __builtin_amdgcn_sched_barrier(0);
#pragma unroll
        for (int kk = 0; kk < 2; ++kk)
            af[1][kk] = *(const bf16x8*)((const char*)sA + b * 8192 + aRd[kk] + 2048);
        __builtin_amdgcn_sched_barrier(0);

        asm volatile("s_waitcnt lgkmcnt(2)" ::: "memory");
        __builtin_amdgcn_sched_barrier(0);
        __builtin_amdgcn_s_setprio(1);
#pragma unroll
        for (int nf = 0; nf < 3; ++nf)
#pragma unroll
            for (int kk = 0; kk < 2; ++kk)
                acc[0][nf] = __builtin_amdgcn_mfma_f32_16x16x32_bf16(
                    af[0][kk], bfr[nf][kk], acc[0][nf], 0, 0, 0);
        __builtin_amdgcn_sched_barrier(0);
        asm volatile("s_waitcnt lgkmcnt(0)" ::: "memory");
        __builtin_amdgcn_sched_barrier(0);
#pragma unroll
        for (int nf = 0; nf < 3; ++nf)
#pragma unroll
            for (int kk = 0; kk < 2; ++kk)
                acc[1][nf] = __builtin_amdgcn_mfma_f32_16x16x32_bf16(
                    af[1][kk], bfr[nf][kk], acc[1][nf], 0, 0, 0);
        __builtin_amdgcn_s_setprio(0);
        __builtin_amdgcn_sched_barrier(0);
        asm volatile("s_waitcnt vmcnt(0)" ::: "memory");
    }
#undef STA64
#undef STB64

    const int rowBase = m0 + wm + quad * 4;
    const int colBase = n0 + wn + l15;
#pragma unroll
    for (int nf = 0; nf < 3; ++nf) {
        const int col = colBase + nf * 16;
        const float bv = BIAS ? bias[col] : 0.0f;
#pragma unroll
        for (int mf = 0; mf < 2; ++mf) {
            const int row = rowBase + mf * 16;
#pragma unroll
            for (int r = 0; r < 4; ++r)
                C[(size_t)(row + r) * ldc + col] = (CT)(acc[mf][nf][r] + bv);
        }
    }
}

// ---------------------------------------------------------------------------
// QKNorm (fp32 RMS over head_dim=128) + RoPE + rearrange.
//  qkv [L][9216] bf16 -> Qh/Kh [24][2048][128] (normed+roped), Vt [24][128][2048].
// ---------------------------------------------------------------------------
__global__ __launch_bounds__(256)
void qk_rope_rearrange(const bf16* __restrict__ qkv, const float* __restrict__ pe,
                       const float* __restrict__ qs, const float* __restrict__ ks,
                       bf16* __restrict__ Qh, bf16* __restrict__ Kh, bf16* __restrict__ Vt)
{
    const int lane = threadIdx.x & 63;
    const int wid  = threadIdx.x >> 6;
    const int idx  = blockIdx.x * 4 + wid;     // = h*2048 + l
    const int h = idx >> 11;
    const int l = idx & 2047;

    const size_t rowb = (size_t)l * 9216 + h * 128 + 2 * lane;
    const float q0 = (float)qkv[rowb];
    const float q1 = (float)qkv[rowb + 1];
    const float k0 = (float)qkv[rowb + 3072];
    const float k1 = (float)qkv[rowb + 3073];
    const bf16  v0 = qkv[rowb + 6144];
    const bf16  v1 = qkv[rowb + 6145];

    float ssq = q0 * q0 + q1 * q1;
    float ssk = k0 * k0 + k1 * k1;
#pragma unroll
    for (int off = 1; off < 64; off <<= 1) {
        ssq += __shfl_xor(ssq, off);
        ssk += __shfl_xor(ssk, off);
    }
    const float rq = rsqrtf(ssq * (1.0f / 128.0f) + 1e-6f);
    const float rk = rsqrtf(ssk * (1.0f / 128.0f) + 1e-6f);

    const float s0q = qs[2 * lane], s1q = qs[2 * lane + 1];
    const float s0k = ks[2 * lane], s1k = ks[2 * lane + 1];

    const float qn0 = (q0 * rq) * s0q;
    const float qn1 = (q1 * rq) * s1q;
    const float kn0 = (k0 * rk) * s0k;
    const float kn1 = (k1 * rk) * s1k;

    const float* pp = pe + ((size_t)l * 64 + lane) * 4;
    const float p00 = pp[0], p01 = pp[1];
    const float p10 = pp[2], p11 = pp[3];

    const bf16 qo0 = (bf16)(p00 * qn0 + p01 * qn1);
    const bf16 qo1 = (bf16)(p10 * qn0 + p11 * qn1);
    const bf16 ko0 = (bf16)(p00 * kn0 + p01 * kn1);
    const bf16 ko1 = (bf16)(p10 * kn0 + p11 * kn1);

    const size_t ob = ((size_t)h * 2048 + l) * 128 + 2 * lane;
    Qh[ob] = qo0; Qh[ob + 1] = qo1;
    Kh[ob] = ko0; Kh[ob + 1] = ko1;

    const size_t vb = ((size_t)h * 128 + 2 * lane) * 2048 + l;
    Vt[vb]        = v0;
    Vt[vb + 2048] = v1;
}

// ---------------------------------------------------------------------------
// Flash attention v4. Block = 4 waves x 16 q-rows = 64 q; kv-steps of 64.
//  - K/V staged via async global_load_lds into XOR-swizzled dbuf LDS tiles;
//    ONE barrier per step; DMA for s+1 overlaps compute of s.
//  - SWAPPED QK^T: mfma(K,Q) -> lane holds P[kv=nt*16+quad*4+r][q=l15];
//    4 consecutive kv per nt pack into ONE bf16x4 ds_write_b64
//    (was 16 scalar ds_write_b16). Loads unchanged under the swap
//    (A/B frags of 16x16x32 read identical row/k slices).
//  - No-max softmax: p = exp(s/sqrt(d)); row-sum via 2 MFMAs vs ones.
//  - setprio(1) around MFMA clusters (T5).
// ---------------------------------------------------------------------------
__global__ __launch_bounds__(256, 2)
void flash_attn(const bf16* __restrict__ Qh, const bf16* __restrict__ Kh,
                const bf16* __restrict__ Vt, bf16* __restrict__ AO)
{
    __shared__ bf16 sK[2 * 64 * 128];  // [kv][d] swizzled, dbuf, 32 KB
    __shared__ bf16 sV[2 * 128 * 64];  // [d][kv] swizzled, dbuf, 32 KB
    __shared__ bf16 sP[4 * 16 * 72];   // per-wave P [q][kv], stride 72

    const int tid   = threadIdx.x;
    const int lane  = tid & 63;
    const int wid   = tid >> 6;
    const int h     = blockIdx.y;
    const int qw    = blockIdx.x * 64 + wid * 16;
    const int l15   = lane & 15;
    const int quad  = lane >> 4;
    const int quad8 = quad * 8;

    const bf16* Kbase = Kh + (size_t)h * 2048 * 128;
    const bf16* Vbase = Vt + (size_t)h * 128 * 2048;

    bf16x8 aq[4];
    {
        const bf16* qp = Qh + ((size_t)h * 2048 + qw + l15) * 128 + quad8;
#pragma unroll
        for (int ki = 0; ki < 4; ++ki) aq[ki] = *(const bf16x8*)(qp + ki * 32);
    }

    bf16x8 ones;
#pragma unroll
    for (int i = 0; i < 8; ++i) ones[i] = (bf16)1.0f;

    f32x4 o[8] = {};
    f32x4 lacc = {};

    bf16* sPw = sP + wid * (16 * 72);
    const int slotbase = wid * 64;

#define STAGE_K(kv, buf)                                                         \
    {                                                                            \
        bf16* kb = sK + (buf) * (64 * 128);                                      \
        _Pragma("unroll")                                                        \
        for (int t = 0; t < 4; ++t) {                                            \
            const int sb   = t * 256 + slotbase;                                 \
            const int slot = sb + lane;                                          \
            const int r    = slot >> 4;                                          \
            const int cg   = (slot & 15) ^ (r & 7);                              \
            LDS_LOAD16(Kbase + (size_t)((kv) + r) * 128 + cg * 8, kb + sb * 8);  \
        }                                                                        \
    }
#define STAGE_V(kv, buf)                                                         \
    {                                                                            \
        bf16* vb = sV + (buf) * (128 * 64);                                      \
        _Pragma("unroll")                                                        \
        for (int t = 0; t < 4; ++t) {                                            \
            const int sb   = t * 256 + slotbase;                                 \
            const int slot = sb + lane;                                          \
            const int r    = slot >> 3;                                          \
            const int cg   = (slot & 7) ^ (r & 7);                               \
            LDS_LOAD16(Vbase + (size_t)r * 2048 + (kv) + cg * 8, vb + sb * 8);   \
        }                                                                        \
    }

    STAGE_K(0, 0);
    STAGE_V(0, 0);

    for (int s = 0; s < 32; ++s) {
        __syncthreads();
        if (s < 31) {
            STAGE_K((s + 1) * 64, (s + 1) & 1);
            STAGE_V((s + 1) * 64, (s + 1) & 1);
        }

        const bf16* kb = sK + (s & 1) * (64 * 128);
        const bf16* vb = sV + (s & 1) * (128 * 64);

        // S^T = K Q^T (16 MFMA, swapped operands) -> lane: P[kv][q=l15]
        f32x4 sc[4];
        __builtin_amdgcn_s_setprio(1);
#pragma unroll
        for (int nt = 0; nt < 4; ++nt) {
            f32x4 t = {};
            const int row = nt * 16 + l15;
#pragma unroll
            for (int ki = 0; ki < 4; ++ki) {
                const int pcg = (4 * ki + quad) ^ (l15 & 7);
                bf16x8 bk = *(const bf16x8*)(kb + row * 128 + pcg * 8);
                t = __builtin_amdgcn_mfma_f32_16x16x32_bf16(bk, aq[ki], t, 0, 0, 0);
            }
            sc[nt] = t;
        }
        __builtin_amdgcn_s_setprio(0);

        // p = exp(s*scale); packed write: 4 consecutive kv -> one b64 store.
        // P[q=l15][kv = nt*16 + quad*4 + r]
#pragma unroll
        for (int nt = 0; nt < 4; ++nt) {
            const float scl = 0.08838834764831845f;   // 1/sqrt(128)
            bf16x4 pv;
            pv[0] = (bf16)__expf(sc[nt][0] * scl);
            pv[1] = (bf16)__expf(sc[nt][1] * scl);
            pv[2] = (bf16)__expf(sc[nt][2] * scl);
            pv[3] = (bf16)__expf(sc[nt][3] * scl);
            *(bf16x4*)(sPw + l15 * 72 + nt * 16 + quad * 4) = pv;
        }

        // PV (16 MFMA, V from swizzled sV) + row-sum l (2 MFMA vs ones)
        __builtin_amdgcn_s_setprio(1);
#pragma unroll
        for (int kk = 0; kk < 2; ++kk) {
            bf16x8 pa = *(const bf16x8*)(sPw + l15 * 72 + kk * 32 + quad8);
            lacc = __builtin_amdgcn_mfma_f32_16x16x32_bf16(pa, ones, lacc, 0, 0, 0);
#pragma unroll
            for (int dt = 0; dt < 8; ++dt) {
                const int row = dt * 16 + l15;
                const int pcg = (kk * 4 + quad) ^ (l15 & 7);
                bf16x8 bv = *(const bf16x8*)(vb + row * 64 + pcg * 8);
                o[dt] = __builtin_amdgcn_mfma_f32_16x16x32_bf16(pa, bv, o[dt], 0, 0, 0);
            }
        }
        __builtin_amdgcn_s_setprio(0);
    }
#undef STAGE_K
#undef STAGE_V

#pragma unroll
    for (int r = 0; r < 4; ++r) {
        const float inv = 1.0f / lacc[r];
        const size_t row = qw + quad * 4 + r;
        bf16* op = AO + row * 3072 + h * 128 + l15;
#pragma unroll
        for (int dt = 0; dt < 8; ++dt) op[dt * 16] = (bf16)(o[dt][r] * inv);
    }
}

// ---------------------------------------------------------------------------
extern "C" void kernel_launch(void* const* d_in, const int* in_sizes, int n_in,
                              void* d_out, int out_size, void* d_ws, size_t ws_size,
                              hipStream_t stream)
{
    (void)in_sizes; (void)n_in; (void)out_size;

    const float* x      = (const float*)d_in[0];
    const float* pe     = (const float*)d_in[1];
    const float* w_qkv  = (const float*)d_in[2];
    const float* w_proj = (const float*)d_in[3];
    const float* b_proj = (const float*)d_in[4];
    const float* q_s    = (const float*)d_in[5];
    const float* k_s    = (const float*)d_in[6];
    float* out = (float*)d_out;

    const size_t NEED_BIG = ((size_t)6291456 + 28311552 + 18874368 + 6291456) * 2; // 119.5 MB

    if (ws_size >= NEED_BIG) {
        // single-launch QKV path
        bf16* xb  = (bf16*)d_ws;                  //  6291456  x bf16
        bf16* wb  = xb + (size_t)6291456;         // 28311552  w_qkv bf16
        bf16* qkv = wb + (size_t)28311552;        // 18874368  [2048][9216]
        bf16* Vt  = qkv + (size_t)18874368;       //  6291456  [24][128][2048]
        bf16* Qh  = xb;                           // alias after GEMM
        bf16* Kh  = wb;                           // alias after GEMM
        bf16* wpb = qkv;                          // alias after rearrange
        bf16* AO  = qkv + (size_t)9437184;

        f32_to_bf16<<<dim3(3072),  256, 0, stream>>>(x,     xb, 786432);
        f32_to_bf16<<<dim3(13824), 256, 0, stream>>>(w_qkv, wb, 3538944);
        // 128x192 GEMM @ 2 blocks/CU: grid 48x16 = 768 blocks = exactly 3/CU
        gemm128_bt<0, bf16><<<dim3(48, 16), 512, 0, stream>>>(xb, wb, nullptr, qkv, 3072, 9216);
        qk_rope_rearrange<<<dim3(12288), 256, 0, stream>>>(qkv, pe, q_s, k_s, Qh, Kh, Vt);
        f32_to_bf16<<<dim3(4608), 256, 0, stream>>>(w_proj, wpb, 1179648);
        flash_attn<<<dim3(32, 24), 256, 0, stream>>>(Qh, Kh, Vt, AO);
        // 64x192 proj GEMM @ 2 blocks/CU: grid 16x32 = 512 blocks = exactly 2/CU
        gemm64_bt<1, float><<<dim3(16, 32), 512, 0, stream>>>(AO, wpb, b_proj, out, 3072, 3072);
    } else {
        // chunked fallback (78.6 MB peak)
        bf16* xb  = (bf16*)d_ws;
        bf16* wb  = xb + (size_t)6291456;
        bf16* qkv = wb + (size_t)9437184;
        bf16* Vt  = qkv + (size_t)18874368;
        bf16* Qh  = xb;
        bf16* Kh  = wb;
        bf16* wpb = qkv;
        bf16* AO  = qkv + (size_t)9437184;

        f32_to_bf16<<<dim3(3072), 256, 0, stream>>>(x, xb, 786432);
        for (int c = 0; c < 3; ++c) {
            f32_to_bf16<<<dim3(4608), 256, 0, stream>>>(w_qkv + (size_t)c * 9437184, wb, 1179648);
            gemm_bt<0, bf16><<<dim3(24, 16), 256, 0, stream>>>(xb, wb, nullptr, qkv + c * 3072, 3072, 9216);
        }
        qk_rope_rearrange<<<dim3(12288), 256, 0, stream>>>(qkv, pe, q_s, k_s, Qh, Kh, Vt);
        f32_to_bf16<<<dim3(4608), 256, 0, stream>>>(w_proj, wpb, 1179648);
        flash_attn<<<dim3(32, 24), 256, 0, stream>>>(Qh, Kh, Vt, AO);
        gemm64_bt<1, float><<<dim3(16, 32), 512, 0, stream>>>(AO, wpb, b_proj, out, 3072, 3072);
    }
}

// Round 7
// 519.838 us; speedup vs baseline: 1.0388x; 1.0196x over previous
//
#include <hip/hip_runtime.h>

typedef __bf16 bf16;
typedef __attribute__((ext_vector_type(4))) __bf16 bf16x4;
typedef __attribute__((ext_vector_type(8))) __bf16 bf16x8;
typedef __attribute__((ext_vector_type(4))) float f32x4;

typedef __attribute__((address_space(1))) void gvoid_t;
typedef __attribute__((address_space(3))) void lvoid_t;

#define LDS_LOAD16(gp, lp) \
    __builtin_amdgcn_global_load_lds((gvoid_t*)(gp), (lvoid_t*)(lp), 16, 0, 0)

// ---------------------------------------------------------------------------
// fp32 -> bf16 conversion, 8 elems/thread (two float4 loads, one 16B store).
// ---------------------------------------------------------------------------
__global__ __launch_bounds__(256)
void f32_to_bf16(const float* __restrict__ in, bf16* __restrict__ out, int n8)
{
    const int i = blockIdx.x * 256 + threadIdx.x;
    if (i >= n8) return;
    const float4 a = ((const float4*)in)[i * 2];
    const float4 b = ((const float4*)in)[i * 2 + 1];
    bf16x8 o;
    o[0] = (bf16)a.x; o[1] = (bf16)a.y; o[2] = (bf16)a.z; o[3] = (bf16)a.w;
    o[4] = (bf16)b.x; o[5] = (bf16)b.y; o[6] = (bf16)b.z; o[7] = (bf16)b.w;
    *(bf16x8*)(out + (size_t)i * 8) = o;
}

// ---------------------------------------------------------------------------
// Legacy 128x128 GEMM (kept for chunked-fallback QKV path).
// ---------------------------------------------------------------------------
template <int BIAS, typename CT>
__global__ __launch_bounds__(256, 2)
void gemm_bt(const bf16* __restrict__ A, const bf16* __restrict__ B,
             const float* __restrict__ bias, CT* __restrict__ C,
             int K, int ldc)
{
    __shared__ bf16 sA[128 * 32];
    __shared__ bf16 sB[128 * 32];
    const int tid  = threadIdx.x;
    const int lane = tid & 63;
    const int wid  = tid >> 6;
    const int m0 = blockIdx.y * 128;
    const int n0 = blockIdx.x * 128;
    const int wm = (wid >> 1) * 64;
    const int wn = (wid & 1) * 64;
    const int l15   = lane & 15;
    const int quad8 = (lane >> 4) * 8;

    f32x4 acc[4][4] = {};

    for (int k0 = 0; k0 < K; k0 += 32) {
#pragma unroll
        for (int t = 0; t < 2; ++t) {
            const int e  = (t * 4 + wid) * 512;
            const int ge = e + lane * 8;
            const int r = ge >> 5, c = ge & 31;
            LDS_LOAD16(A + (size_t)(m0 + r) * K + k0 + c, sA + e);
            LDS_LOAD16(B + (size_t)(n0 + r) * K + k0 + c, sB + e);
        }
        __syncthreads();

        bf16x8 af[4], bfr[4];
#pragma unroll
        for (int i = 0; i < 4; ++i) {
            af[i]  = *(const bf16x8*)(sA + (wm + i * 16 + l15) * 32 + quad8);
            bfr[i] = *(const bf16x8*)(sB + (wn + i * 16 + l15) * 32 + quad8);
        }
#pragma unroll
        for (int i = 0; i < 4; ++i)
#pragma unroll
            for (int j = 0; j < 4; ++j)
                acc[i][j] = __builtin_amdgcn_mfma_f32_16x16x32_bf16(af[i], bfr[j], acc[i][j], 0, 0, 0);
        __syncthreads();
    }

    const int rowBase = m0 + wm + (lane >> 4) * 4;
    const int colBase = n0 + wn + l15;
#pragma unroll
    for (int j = 0; j < 4; ++j) {
        const int col = colBase + j * 16;
        const float bv = BIAS ? bias[col] : 0.0f;
#pragma unroll
        for (int i = 0; i < 4; ++i) {
            const int row = rowBase + i * 16;
#pragma unroll
            for (int r = 0; r < 4; ++r)
                C[(size_t)(row + r) * ldc + col] = (CT)(acc[i][j][r] + bv);
        }
    }
}

// ---------------------------------------------------------------------------
// 128x192 GEMM @ 2 blocks/CU (round-3 proven: 124 us on QKV shape, 932 TF).
//  8 waves (2Mx4N), per-wave 64x48. BK=64, dbuf XOR-swizzled LDS = 80 KiB.
//  16 waves/CU: co-resident block absorbs barrier/vmcnt idle.
// ---------------------------------------------------------------------------
template <int BIAS, typename CT>
__global__ __launch_bounds__(512, 4)
void gemm128_bt(const bf16* __restrict__ A, const bf16* __restrict__ B,
                const float* __restrict__ bias, CT* __restrict__ C,
                int K, int ldc)
{
    __shared__ bf16 sA[2 * 128 * 64];   // 32 KiB
    __shared__ bf16 sB[2 * 192 * 64];   // 48 KiB

    const int tid  = threadIdx.x;
    const int lane = tid & 63;
    const int wid  = tid >> 6;
    const int m0 = blockIdx.y * 128;
    const int n0 = blockIdx.x * 192;
    const int wm = (wid >> 2) * 64;
    const int wn = (wid & 3) * 48;
    const int l15  = lane & 15;
    const int quad = lane >> 4;

    int aoff[2], boff[3];
    int adst[2], bdst[3];
#pragma unroll
    for (int t = 0; t < 2; ++t) {
        const int slot = t * 512 + tid;
        const int r  = slot >> 3;
        const int cg = (slot & 7) ^ (r & 7);
        aoff[t] = (m0 + r) * K + cg * 8;
        adst[t] = (t * 512 + wid * 64) * 8;
    }
#pragma unroll
    for (int t = 0; t < 3; ++t) {
        const int slot = t * 512 + tid;
        const int r  = slot >> 3;
        const int cg = (slot & 7) ^ (r & 7);
        boff[t] = (n0 + r) * K + cg * 8;
        bdst[t] = (t * 512 + wid * 64) * 8;
    }

#define STA(t, kt, buf) LDS_LOAD16(A + (size_t)aoff[t] + (kt) * 64, sA + (buf) * 8192  + adst[t])
#define STB(t, kt, buf) LDS_LOAD16(B + (size_t)boff[t] + (kt) * 64, sB + (buf) * 12288 + bdst[t])

    int aRd[2], bRd[2];
#pragma unroll
    for (int kk = 0; kk < 2; ++kk) {
        const int pcg = (kk * 4 + quad) ^ (l15 & 7);
        aRd[kk] = (wm + l15) * 128 + pcg * 16;
        bRd[kk] = (wn + l15) * 128 + pcg * 16;
    }

    f32x4 acc[4][3] = {};

#pragma unroll
    for (int t = 0; t < 2; ++t) STA(t, 0, 0);
#pragma unroll
    for (int t = 0; t < 3; ++t) STB(t, 0, 0);
    asm volatile("s_waitcnt vmcnt(0)" ::: "memory");

    const int NT = K >> 6;
#pragma unroll 1
    for (int u = 0; u < NT; ++u) {
        const int b = u & 1;
        __builtin_amdgcn_s_barrier();
        if (u + 1 < NT) {
            STA(0, u + 1, b ^ 1); STA(1, u + 1, b ^ 1);
            STB(0, u + 1, b ^ 1); STB(1, u + 1, b ^ 1); STB(2, u + 1, b ^ 1);
        }
        __builtin_amdgcn_sched_barrier(0);

        bf16x8 af[4][2], bfr[3][2];
#pragma unroll
        for (int mi = 0; mi < 2; ++mi)
#pragma unroll
            for (int kk = 0; kk < 2; ++kk)
                af[mi][kk] = *(const bf16x8*)((const char*)sA + b * 16384 +
                                              aRd[kk] + mi * 2048);
#pragma unroll
        for (int nf = 0; nf < 3; ++nf)
#pragma unroll
            for (int kk = 0; kk < 2; ++kk)
                bfr[nf][kk] = *(const bf16x8*)((const char*)sB + b * 24576 +
                                               bRd[kk] + nf * 2048);
        __builtin_amdgcn_sched_barrier(0);
#pragma unroll
        for (int mi = 2; mi < 4; ++mi)
#pragma unroll
            for (int kk = 0; kk < 2; ++kk)
                af[mi][kk] = *(const bf16x8*)((const char*)sA + b * 16384 +
                                              aRd[kk] + mi * 2048);
        __builtin_amdgcn_sched_barrier(0);

        asm volatile("s_waitcnt lgkmcnt(4)" ::: "memory");
        __builtin_amdgcn_sched_barrier(0);
        __builtin_amdgcn_s_setprio(1);
#pragma unroll
        for (int mi = 0; mi < 2; ++mi)
#pragma unroll
            for (int nf = 0; nf < 3; ++nf)
#pragma unroll
                for (int kk = 0; kk < 2; ++kk)
                    acc[mi][nf] = __builtin_amdgcn_mfma_f32_16x16x32_bf16(
                        af[mi][kk], bfr[nf][kk], acc[mi][nf], 0, 0, 0);
        __builtin_amdgcn_sched_barrier(0);
        asm volatile("s_waitcnt lgkmcnt(0)" ::: "memory");
        __builtin_amdgcn_sched_barrier(0);
#pragma unroll
        for (int mi = 2; mi < 4; ++mi)
#pragma unroll
            for (int nf = 0; nf < 3; ++nf)
#pragma unroll
                for (int kk = 0; kk < 2; ++kk)
                    acc[mi][nf] = __builtin_amdgcn_mfma_f32_16x16x32_bf16(
                        af[mi][kk], bfr[nf][kk], acc[mi][nf], 0, 0, 0);
        __builtin_amdgcn_s_setprio(0);
        __builtin_amdgcn_sched_barrier(0);
        asm volatile("s_waitcnt vmcnt(0)" ::: "memory");
    }
#undef STA
#undef STB

    const int rowBase = m0 + wm + quad * 4;
    const int colBase = n0 + wn + l15;
#pragma unroll
    for (int nf = 0; nf < 3; ++nf) {
        const int col = colBase + nf * 16;
        const float bv = BIAS ? bias[col] : 0.0f;
#pragma unroll
        for (int mf = 0; mf < 4; ++mf) {
            const int row = rowBase + mf * 16;
#pragma unroll
            for (int r = 0; r < 4; ++r)
                C[(size_t)(row + r) * ldc + col] = (CT)(acc[mf][nf][r] + bv);
        }
    }
}

// ---------------------------------------------------------------------------
// 64x192 proj GEMM @ 2 blocks/CU (round-3 proven). 8 waves = 2M x 4N;
//  per-wave 32x48. LDS 64 KiB. Grid 16x32 = 512 blocks = exactly 2/CU.
// ---------------------------------------------------------------------------
template <int BIAS, typename CT>
__global__ __launch_bounds__(512, 4)
void gemm64_bt(const bf16* __restrict__ A, const bf16* __restrict__ B,
               const float* __restrict__ bias, CT* __restrict__ C,
               int K, int ldc)
{
    __shared__ bf16 sA[2 * 64 * 64];    // 16 KiB
    __shared__ bf16 sB[2 * 192 * 64];   // 48 KiB

    const int tid  = threadIdx.x;
    const int lane = tid & 63;
    const int wid  = tid >> 6;
    const int m0 = blockIdx.y * 64;
    const int n0 = blockIdx.x * 192;
    const int wm = (wid >> 2) * 32;
    const int wn = (wid & 3) * 48;
    const int l15  = lane & 15;
    const int quad = lane >> 4;

    int aoff, adst;
    {
        const int slot = tid;
        const int r  = slot >> 3;
        const int cg = (slot & 7) ^ (r & 7);
        aoff = (m0 + r) * K + cg * 8;
        adst = (wid * 64) * 8;
    }
    int boff[3], bdst[3];
#pragma unroll
    for (int t = 0; t < 3; ++t) {
        const int slot = t * 512 + tid;
        const int r  = slot >> 3;
        const int cg = (slot & 7) ^ (r & 7);
        boff[t] = (n0 + r) * K + cg * 8;
        bdst[t] = (t * 512 + wid * 64) * 8;
    }

#define STA64(kt, buf)    LDS_LOAD16(A + (size_t)aoff    + (kt) * 64, sA + (buf) * 4096  + adst)
#define STB64(t, kt, buf) LDS_LOAD16(B + (size_t)boff[t] + (kt) * 64, sB + (buf) * 12288 + bdst[t])

    int aRd[2], bRd[2];
#pragma unroll
    for (int kk = 0; kk < 2; ++kk) {
        const int pcg = (kk * 4 + quad) ^ (l15 & 7);
        aRd[kk] = (wm + l15) * 128 + pcg * 16;
        bRd[kk] = (wn + l15) * 128 + pcg * 16;
    }

    f32x4 acc[2][3] = {};

    STA64(0, 0);
#pragma unroll
    for (int t = 0; t < 3; ++t) STB64(t, 0, 0);
    asm volatile("s_waitcnt vmcnt(0)" ::: "memory");

    const int NT = K >> 6;
#pragma unroll 1
    for (int u = 0; u < NT; ++u) {
        const int b = u & 1;
        __builtin_amdgcn_s_barrier();
        if (u + 1 < NT) {
            STA64(u + 1, b ^ 1);
            STB64(0, u + 1, b ^ 1); STB64(1, u + 1, b ^ 1); STB64(2, u + 1, b ^ 1);
        }
        __builtin_amdgcn_sched_barrier(0);

        bf16x8 af[2][2], bfr[3][2];
#pragma unroll
        for (int kk = 0; kk < 2; ++kk)
            af[0][kk] = *(const bf16x8*)((const char*)sA + b * 8192 + aRd[kk]);
#pragma unroll
        for (int nf = 0; nf < 3; ++nf)
#pragma unroll
            for (int kk = 0; kk < 2; ++kk)
                bfr[nf][kk] = *(const bf16x8*)((const char*)sB + b * 24576 +
                                               bRd[kk] + nf * 2048);
        __builtin_amdgcn_sched_barrier(0);
#pragma unroll
        for (int kk = 0; kk < 2; ++kk)
            af[1][kk] = *(const bf16x8*)((const char*)sA + b * 8192 + aRd[kk] + 2048);
        __builtin_amdgcn_sched_barrier(0);

        asm volatile("s_waitcnt lgkmcnt(2)" ::: "memory");
        __builtin_amdgcn_sched_barrier(0);
        __builtin_amdgcn_s_setprio(1);
#pragma unroll
        for (int nf = 0; nf < 3; ++nf)
#pragma unroll
            for (int kk = 0; kk < 2; ++kk)
                acc[0][nf] = __builtin_amdgcn_mfma_f32_16x16x32_bf16(
                    af[0][kk], bfr[nf][kk], acc[0][nf], 0, 0, 0);
        __builtin_amdgcn_sched_barrier(0);
        asm volatile("s_waitcnt lgkmcnt(0)" ::: "memory");
        __builtin_amdgcn_sched_barrier(0);
#pragma unroll
        for (int nf = 0; nf < 3; ++nf)
#pragma unroll
            for (int kk = 0; kk < 2; ++kk)
                acc[1][nf] = __builtin_amdgcn_mfma_f32_16x16x32_bf16(
                    af[1][kk], bfr[nf][kk], acc[1][nf], 0, 0, 0);
        __builtin_amdgcn_s_setprio(0);
        __builtin_amdgcn_sched_barrier(0);
        asm volatile("s_waitcnt vmcnt(0)" ::: "memory");
    }
#undef STA64
#undef STB64

    const int rowBase = m0 + wm + quad * 4;
    const int colBase = n0 + wn + l15;
#pragma unroll
    for (int nf = 0; nf < 3; ++nf) {
        const int col = colBase + nf * 16;
        const float bv = BIAS ? bias[col] : 0.0f;
#pragma unroll
        for (int mf = 0; mf < 2; ++mf) {
            const int row = rowBase + mf * 16;
#pragma unroll
            for (int r = 0; r < 4; ++r)
                C[(size_t)(row + r) * ldc + col] = (CT)(acc[mf][nf][r] + bv);
        }
    }
}

// ---------------------------------------------------------------------------
// QKNorm (fp32 RMS over head_dim=128) + RoPE + rearrange.
//  qkv [L][9216] bf16 -> Qh/Kh [24][2048][128] (normed+roped), Vt [24][128][2048].
// ---------------------------------------------------------------------------
__global__ __launch_bounds__(256)
void qk_rope_rearrange(const bf16* __restrict__ qkv, const float* __restrict__ pe,
                       const float* __restrict__ qs, const float* __restrict__ ks,
                       bf16* __restrict__ Qh, bf16* __restrict__ Kh, bf16* __restrict__ Vt)
{
    const int lane = threadIdx.x & 63;
    const int wid  = threadIdx.x >> 6;
    const int idx  = blockIdx.x * 4 + wid;     // = h*2048 + l
    const int h = idx >> 11;
    const int l = idx & 2047;

    const size_t rowb = (size_t)l * 9216 + h * 128 + 2 * lane;
    const float q0 = (float)qkv[rowb];
    const float q1 = (float)qkv[rowb + 1];
    const float k0 = (float)qkv[rowb + 3072];
    const float k1 = (float)qkv[rowb + 3073];
    const bf16  v0 = qkv[rowb + 6144];
    const bf16  v1 = qkv[rowb + 6145];

    float ssq = q0 * q0 + q1 * q1;
    float ssk = k0 * k0 + k1 * k1;
#pragma unroll
    for (int off = 1; off < 64; off <<= 1) {
        ssq += __shfl_xor(ssq, off);
        ssk += __shfl_xor(ssk, off);
    }
    const float rq = rsqrtf(ssq * (1.0f / 128.0f) + 1e-6f);
    const float rk = rsqrtf(ssk * (1.0f / 128.0f) + 1e-6f);

    const float s0q = qs[2 * lane], s1q = qs[2 * lane + 1];
    const float s0k = ks[2 * lane], s1k = ks[2 * lane + 1];

    const float qn0 = (q0 * rq) * s0q;
    const float qn1 = (q1 * rq) * s1q;
    const float kn0 = (k0 * rk) * s0k;
    const float kn1 = (k1 * rk) * s1k;

    const float* pp = pe + ((size_t)l * 64 + lane) * 4;
    const float p00 = pp[0], p01 = pp[1];
    const float p10 = pp[2], p11 = pp[3];

    const bf16 qo0 = (bf16)(p00 * qn0 + p01 * qn1);
    const bf16 qo1 = (bf16)(p10 * qn0 + p11 * qn1);
    const bf16 ko0 = (bf16)(p00 * kn0 + p01 * kn1);
    const bf16 ko1 = (bf16)(p10 * kn0 + p11 * kn1);

    const size_t ob = ((size_t)h * 2048 + l) * 128 + 2 * lane;
    Qh[ob] = qo0; Qh[ob + 1] = qo1;
    Kh[ob] = ko0; Kh[ob + 1] = ko1;

    const size_t vb = ((size_t)h * 128 + 2 * lane) * 2048 + l;
    Vt[vb]        = v0;
    Vt[vb + 2048] = v1;
}

// ---------------------------------------------------------------------------
// Flash attention v5. Block = 4 waves x 32 q-rows = 128 q; kv-steps of 64.
//  - 2x arithmetic intensity vs v4: each K/V staging serves 2 q-halves
//    (flash was K/V-restaging-bound: staging 2340 cy vs 1320 cy MFMA per
//    step per CU at 16 q/wave). Grid 16x24 = 384 blocks, one full round.
//  - K/V async global_load_lds, XOR-swizzled, dbuf; ONE barrier per step.
//  - Swapped QK^T (round-5 verified layout): lane holds P[kv][q=l15];
//    packed bf16x4 P-writes. sP (16 rows/wave) reused for the two q-halves
//    sequentially: write P(h) -> wave-local lgkmcnt(0) -> PV(h). No extra
//    barrier (per-wave buffer); sched_barrier pins order (rule 18).
//  - No-max softmax: p = exp(s/sqrt(d)); row-sum via MFMA vs ones.
// ---------------------------------------------------------------------------
__global__ __launch_bounds__(256, 2)
void flash_attn(const bf16* __restrict__ Qh, const bf16* __restrict__ Kh,
                const bf16* __restrict__ Vt, bf16* __restrict__ AO)
{
    __shared__ bf16 sK[2 * 64 * 128];  // [kv][d] swizzled, dbuf, 32 KB
    __shared__ bf16 sV[2 * 128 * 64];  // [d][kv] swizzled, dbuf, 32 KB
    __shared__ bf16 sP[4 * 16 * 72];   // per-wave P [q16][kv64], stride 72

    const int tid   = threadIdx.x;
    const int lane  = tid & 63;
    const int wid   = tid >> 6;
    const int h     = blockIdx.y;
    const int qw    = blockIdx.x * 128 + wid * 32;
    const int l15   = lane & 15;
    const int quad  = lane >> 4;
    const int quad8 = quad * 8;

    const bf16* Kbase = Kh + (size_t)h * 2048 * 128;
    const bf16* Vbase = Vt + (size_t)h * 128 * 2048;

    // Q fragments for both q-halves (B-operand of swapped QK^T)
    bf16x8 aq[2][4];
#pragma unroll
    for (int hh = 0; hh < 2; ++hh) {
        const bf16* qp = Qh + ((size_t)h * 2048 + qw + hh * 16 + l15) * 128 + quad8;
#pragma unroll
        for (int ki = 0; ki < 4; ++ki) aq[hh][ki] = *(const bf16x8*)(qp + ki * 32);
    }

    bf16x8 ones;
#pragma unroll
    for (int i = 0; i < 8; ++i) ones[i] = (bf16)1.0f;

    f32x4 o[2][8] = {};
    f32x4 lacc[2] = {};

    bf16* sPw = sP + wid * (16 * 72);
    const int slotbase = wid * 64;

#define STAGE_K(kv, buf)                                                         \
    {                                                                            \
        bf16* kb = sK + (buf) * (64 * 128);                                      \
        _Pragma("unroll")                                                        \
        for (int t = 0; t < 4; ++t) {                                            \
            const int sb   = t * 256 + slotbase;                                 \
            const int slot = sb + lane;                                          \
            const int r    = slot >> 4;                                          \
            const int cg   = (slot & 15) ^ (r & 7);                              \
            LDS_LOAD16(Kbase + (size_t)((kv) + r) * 128 + cg * 8, kb + sb * 8);  \
        }                                                                        \
    }
#define STAGE_V(kv, buf)                                                         \
    {                                                                            \
        bf16* vb = sV + (buf) * (128 * 64);                                      \
        _Pragma("unroll")                                                        \
        for (int t = 0; t < 4; ++t) {                                            \
            const int sb   = t * 256 + slotbase;                                 \
            const int slot = sb + lane;                                          \
            const int r    = slot >> 3;                                          \
            const int cg   = (slot & 7) ^ (r & 7);                               \
            LDS_LOAD16(Vbase + (size_t)r * 2048 + (kv) + cg * 8, vb + sb * 8);   \
        }                                                                        \
    }

    STAGE_K(0, 0);
    STAGE_V(0, 0);

    for (int s = 0; s < 32; ++s) {
        __syncthreads();
        if (s < 31) {
            STAGE_K((s + 1) * 64, (s + 1) & 1);
            STAGE_V((s + 1) * 64, (s + 1) & 1);
        }

        const bf16* kb = sK + (s & 1) * (64 * 128);
        const bf16* vb = sV + (s & 1) * (128 * 64);

        // S^T = K Q^T, both q-halves share each K fragment (32 MFMA, 16 reads)
        f32x4 sc[2][4] = {};
        __builtin_amdgcn_s_setprio(1);
#pragma unroll
        for (int nt = 0; nt < 4; ++nt) {
            const int row = nt * 16 + l15;
#pragma unroll
            for (int ki = 0; ki < 4; ++ki) {
                const int pcg = (4 * ki + quad) ^ (l15 & 7);
                bf16x8 bk = *(const bf16x8*)(kb + row * 128 + pcg * 8);
                sc[0][nt] = __builtin_amdgcn_mfma_f32_16x16x32_bf16(bk, aq[0][ki], sc[0][nt], 0, 0, 0);
                sc[1][nt] = __builtin_amdgcn_mfma_f32_16x16x32_bf16(bk, aq[1][ki], sc[1][nt], 0, 0, 0);
            }
        }
        __builtin_amdgcn_s_setprio(0);

        // Per q-half: packed P write -> wave-local wait -> PV (sP reused)
#pragma unroll
        for (int hh = 0; hh < 2; ++hh) {
            __builtin_amdgcn_sched_barrier(0);   // keep prior PV reads before writes
#pragma unroll
            for (int nt = 0; nt < 4; ++nt) {
                const float scl = 0.08838834764831845f;   // 1/sqrt(128)
                bf16x4 pv;
                pv[0] = (bf16)__expf(sc[hh][nt][0] * scl);
                pv[1] = (bf16)__expf(sc[hh][nt][1] * scl);
                pv[2] = (bf16)__expf(sc[hh][nt][2] * scl);
                pv[3] = (bf16)__expf(sc[hh][nt][3] * scl);
                *(bf16x4*)(sPw + l15 * 72 + nt * 16 + quad * 4) = pv;
            }
            asm volatile("s_waitcnt lgkmcnt(0)" ::: "memory");
            __builtin_amdgcn_sched_barrier(0);

            __builtin_amdgcn_s_setprio(1);
#pragma unroll
            for (int kk = 0; kk < 2; ++kk) {
                bf16x8 pa = *(const bf16x8*)(sPw + l15 * 72 + kk * 32 + quad8);
                lacc[hh] = __builtin_amdgcn_mfma_f32_16x16x32_bf16(pa, ones, lacc[hh], 0, 0, 0);
#pragma unroll
                for (int dt = 0; dt < 8; ++dt) {
                    const int row = dt * 16 + l15;
                    const int pcg = (kk * 4 + quad) ^ (l15 & 7);
                    bf16x8 bv = *(const bf16x8*)(vb + row * 64 + pcg * 8);
                    o[hh][dt] = __builtin_amdgcn_mfma_f32_16x16x32_bf16(pa, bv, o[hh][dt], 0, 0, 0);
                }
            }
            __builtin_amdgcn_s_setprio(0);
        }
    }
#undef STAGE_K
#undef STAGE_V

#pragma unroll
    for (int hh = 0; hh < 2; ++hh)
#pragma unroll
        for (int r = 0; r < 4; ++r) {
            const float inv = 1.0f / lacc[hh][r];
            const size_t row = qw + hh * 16 + quad * 4 + r;
            bf16* op = AO + row * 3072 + h * 128 + l15;
#pragma unroll
            for (int dt = 0; dt < 8; ++dt) op[dt * 16] = (bf16)(o[hh][dt][r] * inv);
        }
}

// ---------------------------------------------------------------------------
extern "C" void kernel_launch(void* const* d_in, const int* in_sizes, int n_in,
                              void* d_out, int out_size, void* d_ws, size_t ws_size,
                              hipStream_t stream)
{
    (void)in_sizes; (void)n_in; (void)out_size;

    const float* x      = (const float*)d_in[0];
    const float* pe     = (const float*)d_in[1];
    const float* w_qkv  = (const float*)d_in[2];
    const float* w_proj = (const float*)d_in[3];
    const float* b_proj = (const float*)d_in[4];
    const float* q_s    = (const float*)d_in[5];
    const float* k_s    = (const float*)d_in[6];
    float* out = (float*)d_out;

    const size_t NEED_BIG = ((size_t)6291456 + 28311552 + 18874368 + 6291456) * 2; // 119.5 MB

    if (ws_size >= NEED_BIG) {
        // single-launch QKV path
        bf16* xb  = (bf16*)d_ws;                  //  6291456  x bf16
        bf16* wb  = xb + (size_t)6291456;         // 28311552  w_qkv bf16
        bf16* qkv = wb + (size_t)28311552;        // 18874368  [2048][9216]
        bf16* Vt  = qkv + (size_t)18874368;       //  6291456  [24][128][2048]
        bf16* Qh  = xb;                           // alias after GEMM
        bf16* Kh  = wb;                           // alias after GEMM
        bf16* wpb = qkv;                          // alias after rearrange
        bf16* AO  = qkv + (size_t)9437184;

        f32_to_bf16<<<dim3(3072),  256, 0, stream>>>(x,     xb, 786432);
        f32_to_bf16<<<dim3(13824), 256, 0, stream>>>(w_qkv, wb, 3538944);
        // 128x192 GEMM @ 2 blocks/CU: grid 48x16 = 768 blocks = exactly 3/CU
        gemm128_bt<0, bf16><<<dim3(48, 16), 512, 0, stream>>>(xb, wb, nullptr, qkv, 3072, 9216);
        qk_rope_rearrange<<<dim3(12288), 256, 0, stream>>>(qkv, pe, q_s, k_s, Qh, Kh, Vt);
        f32_to_bf16<<<dim3(4608), 256, 0, stream>>>(w_proj, wpb, 1179648);
        // flash v5: 128 q/block -> grid 16x24 = 384 blocks, one round @ 2/CU
        flash_attn<<<dim3(16, 24), 256, 0, stream>>>(Qh, Kh, Vt, AO);
        // 64x192 proj GEMM @ 2 blocks/CU: grid 16x32 = 512 blocks = exactly 2/CU
        gemm64_bt<1, float><<<dim3(16, 32), 512, 0, stream>>>(AO, wpb, b_proj, out, 3072, 3072);
    } else {
        // chunked fallback (78.6 MB peak)
        bf16* xb  = (bf16*)d_ws;
        bf16* wb  = xb + (size_t)6291456;
        bf16* qkv = wb + (size_t)9437184;
        bf16* Vt  = qkv + (size_t)18874368;
        bf16* Qh  = xb;
        bf16* Kh  = wb;
        bf16* wpb = qkv;
        bf16* AO  = qkv + (size_t)9437184;

        f32_to_bf16<<<dim3(3072), 256, 0, stream>>>(x, xb, 786432);
        for (int c = 0; c < 3; ++c) {
            f32_to_bf16<<<dim3(4608), 256, 0, stream>>>(w_qkv + (size_t)c * 9437184, wb, 1179648);
            gemm_bt<0, bf16><<<dim3(24, 16), 256, 0, stream>>>(xb, wb, nullptr, qkv + c * 3072, 3072, 9216);
        }
        qk_rope_rearrange<<<dim3(12288), 256, 0, stream>>>(qkv, pe, q_s, k_s, Qh, Kh, Vt);
        f32_to_bf16<<<dim3(4608), 256, 0, stream>>>(w_proj, wpb, 1179648);
        flash_attn<<<dim3(16, 24), 256, 0, stream>>>(Qh, Kh, Vt, AO);
        gemm64_bt<1, float><<<dim3(16, 32), 512, 0, stream>>>(AO, wpb, b_proj, out, 3072, 3072);
    }
}

// Round 8
// 493.255 us; speedup vs baseline: 1.0948x; 1.0539x over previous
//
#include <hip/hip_runtime.h>

typedef __bf16 bf16;
typedef __attribute__((ext_vector_type(4))) __bf16 bf16x4;
typedef __attribute__((ext_vector_type(8))) __bf16 bf16x8;
typedef __attribute__((ext_vector_type(4))) float f32x4;

typedef __attribute__((address_space(1))) void gvoid_t;
typedef __attribute__((address_space(3))) void lvoid_t;

#define LDS_LOAD16(gp, lp) \
    __builtin_amdgcn_global_load_lds((gvoid_t*)(gp), (lvoid_t*)(lp), 16, 0, 0)

// ---------------------------------------------------------------------------
// fp32 -> bf16 conversion, 8 elems/thread (two float4 loads, one 16B store).
// ---------------------------------------------------------------------------
__global__ __launch_bounds__(256)
void f32_to_bf16(const float* __restrict__ in, bf16* __restrict__ out, int n8)
{
    const int i = blockIdx.x * 256 + threadIdx.x;
    if (i >= n8) return;
    const float4 a = ((const float4*)in)[i * 2];
    const float4 b = ((const float4*)in)[i * 2 + 1];
    bf16x8 o;
    o[0] = (bf16)a.x; o[1] = (bf16)a.y; o[2] = (bf16)a.z; o[3] = (bf16)a.w;
    o[4] = (bf16)b.x; o[5] = (bf16)b.y; o[6] = (bf16)b.z; o[7] = (bf16)b.w;
    *(bf16x8*)(out + (size_t)i * 8) = o;
}

// ---------------------------------------------------------------------------
// Legacy 128x128 GEMM (kept for chunked-fallback QKV path).
// ---------------------------------------------------------------------------
template <int BIAS, typename CT>
__global__ __launch_bounds__(256, 2)
void gemm_bt(const bf16* __restrict__ A, const bf16* __restrict__ B,
             const float* __restrict__ bias, CT* __restrict__ C,
             int K, int ldc)
{
    __shared__ bf16 sA[128 * 32];
    __shared__ bf16 sB[128 * 32];
    const int tid  = threadIdx.x;
    const int lane = tid & 63;
    const int wid  = tid >> 6;
    const int m0 = blockIdx.y * 128;
    const int n0 = blockIdx.x * 128;
    const int wm = (wid >> 1) * 64;
    const int wn = (wid & 1) * 64;
    const int l15   = lane & 15;
    const int quad8 = (lane >> 4) * 8;

    f32x4 acc[4][4] = {};

    for (int k0 = 0; k0 < K; k0 += 32) {
#pragma unroll
        for (int t = 0; t < 2; ++t) {
            const int e  = (t * 4 + wid) * 512;
            const int ge = e + lane * 8;
            const int r = ge >> 5, c = ge & 31;
            LDS_LOAD16(A + (size_t)(m0 + r) * K + k0 + c, sA + e);
            LDS_LOAD16(B + (size_t)(n0 + r) * K + k0 + c, sB + e);
        }
        __syncthreads();

        bf16x8 af[4], bfr[4];
#pragma unroll
        for (int i = 0; i < 4; ++i) {
            af[i]  = *(const bf16x8*)(sA + (wm + i * 16 + l15) * 32 + quad8);
            bfr[i] = *(const bf16x8*)(sB + (wn + i * 16 + l15) * 32 + quad8);
        }
#pragma unroll
        for (int i = 0; i < 4; ++i)
#pragma unroll
            for (int j = 0; j < 4; ++j)
                acc[i][j] = __builtin_amdgcn_mfma_f32_16x16x32_bf16(af[i], bfr[j], acc[i][j], 0, 0, 0);
        __syncthreads();
    }

    const int rowBase = m0 + wm + (lane >> 4) * 4;
    const int colBase = n0 + wn + l15;
#pragma unroll
    for (int j = 0; j < 4; ++j) {
        const int col = colBase + j * 16;
        const float bv = BIAS ? bias[col] : 0.0f;
#pragma unroll
        for (int i = 0; i < 4; ++i) {
            const int row = rowBase + i * 16;
#pragma unroll
            for (int r = 0; r < 4; ++r)
                C[(size_t)(row + r) * ldc + col] = (CT)(acc[i][j][r] + bv);
        }
    }
}

// ---------------------------------------------------------------------------
// 128x192 GEMM @ 2 blocks/CU (round-3 proven: 124 us on QKV shape, 932 TF).
//  8 waves (2Mx4N), per-wave 64x48. BK=64, dbuf XOR-swizzled LDS = 80 KiB.
//  16 waves/CU: co-resident block absorbs barrier/vmcnt idle.
// ---------------------------------------------------------------------------
template <int BIAS, typename CT>
__global__ __launch_bounds__(512, 4)
void gemm128_bt(const bf16* __restrict__ A, const bf16* __restrict__ B,
                const float* __restrict__ bias, CT* __restrict__ C,
                int K, int ldc)
{
    __shared__ bf16 sA[2 * 128 * 64];   // 32 KiB
    __shared__ bf16 sB[2 * 192 * 64];   // 48 KiB

    const int tid  = threadIdx.x;
    const int lane = tid & 63;
    const int wid  = tid >> 6;
    const int m0 = blockIdx.y * 128;
    const int n0 = blockIdx.x * 192;
    const int wm = (wid >> 2) * 64;
    const int wn = (wid & 3) * 48;
    const int l15  = lane & 15;
    const int quad = lane >> 4;

    int aoff[2], boff[3];
    int adst[2], bdst[3];
#pragma unroll
    for (int t = 0; t < 2; ++t) {
        const int slot = t * 512 + tid;
        const int r  = slot >> 3;
        const int cg = (slot & 7) ^ (r & 7);
        aoff[t] = (m0 + r) * K + cg * 8;
        adst[t] = (t * 512 + wid * 64) * 8;
    }
#pragma unroll
    for (int t = 0; t < 3; ++t) {
        const int slot = t * 512 + tid;
        const int r  = slot >> 3;
        const int cg = (slot & 7) ^ (r & 7);
        boff[t] = (n0 + r) * K + cg * 8;
        bdst[t] = (t * 512 + wid * 64) * 8;
    }

#define STA(t, kt, buf) LDS_LOAD16(A + (size_t)aoff[t] + (kt) * 64, sA + (buf) * 8192  + adst[t])
#define STB(t, kt, buf) LDS_LOAD16(B + (size_t)boff[t] + (kt) * 64, sB + (buf) * 12288 + bdst[t])

    int aRd[2], bRd[2];
#pragma unroll
    for (int kk = 0; kk < 2; ++kk) {
        const int pcg = (kk * 4 + quad) ^ (l15 & 7);
        aRd[kk] = (wm + l15) * 128 + pcg * 16;
        bRd[kk] = (wn + l15) * 128 + pcg * 16;
    }

    f32x4 acc[4][3] = {};

#pragma unroll
    for (int t = 0; t < 2; ++t) STA(t, 0, 0);
#pragma unroll
    for (int t = 0; t < 3; ++t) STB(t, 0, 0);
    asm volatile("s_waitcnt vmcnt(0)" ::: "memory");

    const int NT = K >> 6;
#pragma unroll 1
    for (int u = 0; u < NT; ++u) {
        const int b = u & 1;
        __builtin_amdgcn_s_barrier();
        if (u + 1 < NT) {
            STA(0, u + 1, b ^ 1); STA(1, u + 1, b ^ 1);
            STB(0, u + 1, b ^ 1); STB(1, u + 1, b ^ 1); STB(2, u + 1, b ^ 1);
        }
        __builtin_amdgcn_sched_barrier(0);

        bf16x8 af[4][2], bfr[3][2];
#pragma unroll
        for (int mi = 0; mi < 2; ++mi)
#pragma unroll
            for (int kk = 0; kk < 2; ++kk)
                af[mi][kk] = *(const bf16x8*)((const char*)sA + b * 16384 +
                                              aRd[kk] + mi * 2048);
#pragma unroll
        for (int nf = 0; nf < 3; ++nf)
#pragma unroll
            for (int kk = 0; kk < 2; ++kk)
                bfr[nf][kk] = *(const bf16x8*)((const char*)sB + b * 24576 +
                                               bRd[kk] + nf * 2048);
        __builtin_amdgcn_sched_barrier(0);
#pragma unroll
        for (int mi = 2; mi < 4; ++mi)
#pragma unroll
            for (int kk = 0; kk < 2; ++kk)
                af[mi][kk] = *(const bf16x8*)((const char*)sA + b * 16384 +
                                              aRd[kk] + mi * 2048);
        __builtin_amdgcn_sched_barrier(0);

        asm volatile("s_waitcnt lgkmcnt(4)" ::: "memory");
        __builtin_amdgcn_sched_barrier(0);
        __builtin_amdgcn_s_setprio(1);
#pragma unroll
        for (int mi = 0; mi < 2; ++mi)
#pragma unroll
            for (int nf = 0; nf < 3; ++nf)
#pragma unroll
                for (int kk = 0; kk < 2; ++kk)
                    acc[mi][nf] = __builtin_amdgcn_mfma_f32_16x16x32_bf16(
                        af[mi][kk], bfr[nf][kk], acc[mi][nf], 0, 0, 0);
        __builtin_amdgcn_sched_barrier(0);
        asm volatile("s_waitcnt lgkmcnt(0)" ::: "memory");
        __builtin_amdgcn_sched_barrier(0);
#pragma unroll
        for (int mi = 2; mi < 4; ++mi)
#pragma unroll
            for (int nf = 0; nf < 3; ++nf)
#pragma unroll
                for (int kk = 0; kk < 2; ++kk)
                    acc[mi][nf] = __builtin_amdgcn_mfma_f32_16x16x32_bf16(
                        af[mi][kk], bfr[nf][kk], acc[mi][nf], 0, 0, 0);
        __builtin_amdgcn_s_setprio(0);
        __builtin_amdgcn_sched_barrier(0);
        asm volatile("s_waitcnt vmcnt(0)" ::: "memory");
    }
#undef STA
#undef STB

    const int rowBase = m0 + wm + quad * 4;
    const int colBase = n0 + wn + l15;
#pragma unroll
    for (int nf = 0; nf < 3; ++nf) {
        const int col = colBase + nf * 16;
        const float bv = BIAS ? bias[col] : 0.0f;
#pragma unroll
        for (int mf = 0; mf < 4; ++mf) {
            const int row = rowBase + mf * 16;
#pragma unroll
            for (int r = 0; r < 4; ++r)
                C[(size_t)(row + r) * ldc + col] = (CT)(acc[mf][nf][r] + bv);
        }
    }
}

// ---------------------------------------------------------------------------
// 64x192 proj GEMM @ 2 blocks/CU (round-3 proven). 8 waves = 2M x 4N;
//  per-wave 32x48. LDS 64 KiB. Grid 16x32 = 512 blocks = exactly 2/CU.
// ---------------------------------------------------------------------------
template <int BIAS, typename CT>
__global__ __launch_bounds__(512, 4)
void gemm64_bt(const bf16* __restrict__ A, const bf16* __restrict__ B,
               const float* __restrict__ bias, CT* __restrict__ C,
               int K, int ldc)
{
    __shared__ bf16 sA[2 * 64 * 64];    // 16 KiB
    __shared__ bf16 sB[2 * 192 * 64];   // 48 KiB

    const int tid  = threadIdx.x;
    const int lane = tid & 63;
    const int wid  = tid >> 6;
    const int m0 = blockIdx.y * 64;
    const int n0 = blockIdx.x * 192;
    const int wm = (wid >> 2) * 32;
    const int wn = (wid & 3) * 48;
    const int l15  = lane & 15;
    const int quad = lane >> 4;

    int aoff, adst;
    {
        const int slot = tid;
        const int r  = slot >> 3;
        const int cg = (slot & 7) ^ (r & 7);
        aoff = (m0 + r) * K + cg * 8;
        adst = (wid * 64) * 8;
    }
    int boff[3], bdst[3];
#pragma unroll
    for (int t = 0; t < 3; ++t) {
        const int slot = t * 512 + tid;
        const int r  = slot >> 3;
        const int cg = (slot & 7) ^ (r & 7);
        boff[t] = (n0 + r) * K + cg * 8;
        bdst[t] = (t * 512 + wid * 64) * 8;
    }

#define STA64(kt, buf)    LDS_LOAD16(A + (size_t)aoff    + (kt) * 64, sA + (buf) * 4096  + adst)
#define STB64(t, kt, buf) LDS_LOAD16(B + (size_t)boff[t] + (kt) * 64, sB + (buf) * 12288 + bdst[t])

    int aRd[2], bRd[2];
#pragma unroll
    for (int kk = 0; kk < 2; ++kk) {
        const int pcg = (kk * 4 + quad) ^ (l15 & 7);
        aRd[kk] = (wm + l15) * 128 + pcg * 16;
        bRd[kk] = (wn + l15) * 128 + pcg * 16;
    }

    f32x4 acc[2][3] = {};

    STA64(0, 0);
#pragma unroll
    for (int t = 0; t < 3; ++t) STB64(t, 0, 0);
    asm volatile("s_waitcnt vmcnt(0)" ::: "memory");

    const int NT = K >> 6;
#pragma unroll 1
    for (int u = 0; u < NT; ++u) {
        const int b = u & 1;
        __builtin_amdgcn_s_barrier();
        if (u + 1 < NT) {
            STA64(u + 1, b ^ 1);
            STB64(0, u + 1, b ^ 1); STB64(1, u + 1, b ^ 1); STB64(2, u + 1, b ^ 1);
        }
        __builtin_amdgcn_sched_barrier(0);

        bf16x8 af[2][2], bfr[3][2];
#pragma unroll
        for (int kk = 0; kk < 2; ++kk)
            af[0][kk] = *(const bf16x8*)((const char*)sA + b * 8192 + aRd[kk]);
#pragma unroll
        for (int nf = 0; nf < 3; ++nf)
#pragma unroll
            for (int kk = 0; kk < 2; ++kk)
                bfr[nf][kk] = *(const bf16x8*)((const char*)sB + b * 24576 +
                                               bRd[kk] + nf * 2048);
        __builtin_amdgcn_sched_barrier(0);
#pragma unroll
        for (int kk = 0; kk < 2; ++kk)
            af[1][kk] = *(const bf16x8*)((const char*)sA + b * 8192 + aRd[kk] + 2048);
        __builtin_amdgcn_sched_barrier(0);

        asm volatile("s_waitcnt lgkmcnt(2)" ::: "memory");
        __builtin_amdgcn_sched_barrier(0);
        __builtin_amdgcn_s_setprio(1);
#pragma unroll
        for (int nf = 0; nf < 3; ++nf)
#pragma unroll
            for (int kk = 0; kk < 2; ++kk)
                acc[0][nf] = __builtin_amdgcn_mfma_f32_16x16x32_bf16(
                    af[0][kk], bfr[nf][kk], acc[0][nf], 0, 0, 0);
        __builtin_amdgcn_sched_barrier(0);
        asm volatile("s_waitcnt lgkmcnt(0)" ::: "memory");
        __builtin_amdgcn_sched_barrier(0);
#pragma unroll
        for (int nf = 0; nf < 3; ++nf)
#pragma unroll
            for (int kk = 0; kk < 2; ++kk)
                acc[1][nf] = __builtin_amdgcn_mfma_f32_16x16x32_bf16(
                    af[1][kk], bfr[nf][kk], acc[1][nf], 0, 0, 0);
        __builtin_amdgcn_s_setprio(0);
        __builtin_amdgcn_sched_barrier(0);
        asm volatile("s_waitcnt vmcnt(0)" ::: "memory");
    }
#undef STA64
#undef STB64

    const int rowBase = m0 + wm + quad * 4;
    const int colBase = n0 + wn + l15;
#pragma unroll
    for (int nf = 0; nf < 3; ++nf) {
        const int col = colBase + nf * 16;
        const float bv = BIAS ? bias[col] : 0.0f;
#pragma unroll
        for (int mf = 0; mf < 2; ++mf) {
            const int row = rowBase + mf * 16;
#pragma unroll
            for (int r = 0; r < 4; ++r)
                C[(size_t)(row + r) * ldc + col] = (CT)(acc[mf][nf][r] + bv);
        }
    }
}

// ---------------------------------------------------------------------------
// QKNorm (fp32 RMS over head_dim=128) + RoPE + rearrange.
//  qkv [L][9216] bf16 -> Qh/Kh [24][2048][128] (normed+roped), Vt [24][128][2048].
// ---------------------------------------------------------------------------
__global__ __launch_bounds__(256)
void qk_rope_rearrange(const bf16* __restrict__ qkv, const float* __restrict__ pe,
                       const float* __restrict__ qs, const float* __restrict__ ks,
                       bf16* __restrict__ Qh, bf16* __restrict__ Kh, bf16* __restrict__ Vt)
{
    const int lane = threadIdx.x & 63;
    const int wid  = threadIdx.x >> 6;
    const int idx  = blockIdx.x * 4 + wid;     // = h*2048 + l
    const int h = idx >> 11;
    const int l = idx & 2047;

    const size_t rowb = (size_t)l * 9216 + h * 128 + 2 * lane;
    const float q0 = (float)qkv[rowb];
    const float q1 = (float)qkv[rowb + 1];
    const float k0 = (float)qkv[rowb + 3072];
    const float k1 = (float)qkv[rowb + 3073];
    const bf16  v0 = qkv[rowb + 6144];
    const bf16  v1 = qkv[rowb + 6145];

    float ssq = q0 * q0 + q1 * q1;
    float ssk = k0 * k0 + k1 * k1;
#pragma unroll
    for (int off = 1; off < 64; off <<= 1) {
        ssq += __shfl_xor(ssq, off);
        ssk += __shfl_xor(ssk, off);
    }
    const float rq = rsqrtf(ssq * (1.0f / 128.0f) + 1e-6f);
    const float rk = rsqrtf(ssk * (1.0f / 128.0f) + 1e-6f);

    const float s0q = qs[2 * lane], s1q = qs[2 * lane + 1];
    const float s0k = ks[2 * lane], s1k = ks[2 * lane + 1];

    const float qn0 = (q0 * rq) * s0q;
    const float qn1 = (q1 * rq) * s1q;
    const float kn0 = (k0 * rk) * s0k;
    const float kn1 = (k1 * rk) * s1k;

    const float* pp = pe + ((size_t)l * 64 + lane) * 4;
    const float p00 = pp[0], p01 = pp[1];
    const float p10 = pp[2], p11 = pp[3];

    const bf16 qo0 = (bf16)(p00 * qn0 + p01 * qn1);
    const bf16 qo1 = (bf16)(p10 * qn0 + p11 * qn1);
    const bf16 ko0 = (bf16)(p00 * kn0 + p01 * kn1);
    const bf16 ko1 = (bf16)(p10 * kn0 + p11 * kn1);

    const size_t ob = ((size_t)h * 2048 + l) * 128 + 2 * lane;
    Qh[ob] = qo0; Qh[ob + 1] = qo1;
    Kh[ob] = ko0; Kh[ob + 1] = ko1;

    const size_t vb = ((size_t)h * 128 + 2 * lane) * 2048 + l;
    Vt[vb]        = v0;
    Vt[vb + 2048] = v1;
}

// ---------------------------------------------------------------------------
// Flash attention v6. Block = 4 waves x 32 q-rows = 128 q; kv-steps of 64.
//  - v5 was LDS-read-bound: 52 KiB ds_read per wave per step, 32 of them V
//    (re-read per q-half). v6 does ONE V pass serving both halves:
//    write P(h0) -> read pa0 -> write P(h1) -> read pa1 -> V loop with
//    2 MFMAs per bv. 36 KiB/step (-31%). Wave-local lgkmcnt(0)+
//    sched_barrier(0) fences at each sP overwrite hazard (rule 18).
//  - K/V async global_load_lds, XOR-swizzled, dbuf; ONE barrier per step.
//  - Swapped QK^T (verified): lane holds P[kv][q=l15]; packed bf16x4 writes.
//  - No-max softmax: p = exp(s/sqrt(d)); row-sum via MFMA vs ones.
// ---------------------------------------------------------------------------
__global__ __launch_bounds__(256, 2)
void flash_attn(const bf16* __restrict__ Qh, const bf16* __restrict__ Kh,
                const bf16* __restrict__ Vt, bf16* __restrict__ AO)
{
    __shared__ bf16 sK[2 * 64 * 128];  // [kv][d] swizzled, dbuf, 32 KB
    __shared__ bf16 sV[2 * 128 * 64];  // [d][kv] swizzled, dbuf, 32 KB
    __shared__ bf16 sP[4 * 16 * 72];   // per-wave P [q16][kv64], stride 72

    const int tid   = threadIdx.x;
    const int lane  = tid & 63;
    const int wid   = tid >> 6;
    const int h     = blockIdx.y;
    const int qw    = blockIdx.x * 128 + wid * 32;
    const int l15   = lane & 15;
    const int quad  = lane >> 4;
    const int quad8 = quad * 8;

    const bf16* Kbase = Kh + (size_t)h * 2048 * 128;
    const bf16* Vbase = Vt + (size_t)h * 128 * 2048;

    // Q fragments for both q-halves (B-operand of swapped QK^T)
    bf16x8 aq[2][4];
#pragma unroll
    for (int hh = 0; hh < 2; ++hh) {
        const bf16* qp = Qh + ((size_t)h * 2048 + qw + hh * 16 + l15) * 128 + quad8;
#pragma unroll
        for (int ki = 0; ki < 4; ++ki) aq[hh][ki] = *(const bf16x8*)(qp + ki * 32);
    }

    bf16x8 ones;
#pragma unroll
    for (int i = 0; i < 8; ++i) ones[i] = (bf16)1.0f;

    f32x4 o[2][8] = {};
    f32x4 lacc[2] = {};

    bf16* sPw = sP + wid * (16 * 72);
    const int slotbase = wid * 64;

#define STAGE_K(kv, buf)                                                         \
    {                                                                            \
        bf16* kb = sK + (buf) * (64 * 128);                                      \
        _Pragma("unroll")                                                        \
        for (int t = 0; t < 4; ++t) {                                            \
            const int sb   = t * 256 + slotbase;                                 \
            const int slot = sb + lane;                                          \
            const int r    = slot >> 4;                                          \
            const int cg   = (slot & 15) ^ (r & 7);                              \
            LDS_LOAD16(Kbase + (size_t)((kv) + r) * 128 + cg * 8, kb + sb * 8);  \
        }                                                                        \
    }
#define STAGE_V(kv, buf)                                                         \
    {                                                                            \
        bf16* vb = sV + (buf) * (128 * 64);                                      \
        _Pragma("unroll")                                                        \
        for (int t = 0; t < 4; ++t) {                                            \
            const int sb   = t * 256 + slotbase;                                 \
            const int slot = sb + lane;                                          \
            const int r    = slot >> 3;                                          \
            const int cg   = (slot & 7) ^ (r & 7);                               \
            LDS_LOAD16(Vbase + (size_t)r * 2048 + (kv) + cg * 8, vb + sb * 8);   \
        }                                                                        \
    }

    STAGE_K(0, 0);
    STAGE_V(0, 0);

    for (int s = 0; s < 32; ++s) {
        __syncthreads();
        if (s < 31) {
            STAGE_K((s + 1) * 64, (s + 1) & 1);
            STAGE_V((s + 1) * 64, (s + 1) & 1);
        }

        const bf16* kb = sK + (s & 1) * (64 * 128);
        const bf16* vb = sV + (s & 1) * (128 * 64);

        // S^T = K Q^T, both q-halves share each K fragment (32 MFMA, 16 reads)
        f32x4 sc[2][4] = {};
        __builtin_amdgcn_s_setprio(1);
#pragma unroll
        for (int nt = 0; nt < 4; ++nt) {
            const int row = nt * 16 + l15;
#pragma unroll
            for (int ki = 0; ki < 4; ++ki) {
                const int pcg = (4 * ki + quad) ^ (l15 & 7);
                bf16x8 bk = *(const bf16x8*)(kb + row * 128 + pcg * 8);
                sc[0][nt] = __builtin_amdgcn_mfma_f32_16x16x32_bf16(bk, aq[0][ki], sc[0][nt], 0, 0, 0);
                sc[1][nt] = __builtin_amdgcn_mfma_f32_16x16x32_bf16(bk, aq[1][ki], sc[1][nt], 0, 0, 0);
            }
        }
        __builtin_amdgcn_s_setprio(0);

        // P(h0) -> pa0, P(h1) -> pa1 (sP reused; wave-local fences), then
        // ONE V pass with 2 MFMAs per bv.
        bf16x8 pa0[2], pa1[2];
#pragma unroll
        for (int hh = 0; hh < 2; ++hh) {
            __builtin_amdgcn_sched_barrier(0);   // prior sP reads before writes
#pragma unroll
            for (int nt = 0; nt < 4; ++nt) {
                const float scl = 0.08838834764831845f;   // 1/sqrt(128)
                bf16x4 pv;
                pv[0] = (bf16)__expf(sc[hh][nt][0] * scl);
                pv[1] = (bf16)__expf(sc[hh][nt][1] * scl);
                pv[2] = (bf16)__expf(sc[hh][nt][2] * scl);
                pv[3] = (bf16)__expf(sc[hh][nt][3] * scl);
                *(bf16x4*)(sPw + l15 * 72 + nt * 16 + quad * 4) = pv;
            }
            asm volatile("s_waitcnt lgkmcnt(0)" ::: "memory");   // writes visible
            __builtin_amdgcn_sched_barrier(0);
            if (hh == 0) {
#pragma unroll
                for (int kk = 0; kk < 2; ++kk)
                    pa0[kk] = *(const bf16x8*)(sPw + l15 * 72 + kk * 32 + quad8);
            } else {
#pragma unroll
                for (int kk = 0; kk < 2; ++kk)
                    pa1[kk] = *(const bf16x8*)(sPw + l15 * 72 + kk * 32 + quad8);
            }
            asm volatile("s_waitcnt lgkmcnt(0)" ::: "memory");   // reads done
            __builtin_amdgcn_sched_barrier(0);                   // before overwrite
        }

        __builtin_amdgcn_s_setprio(1);
        lacc[0] = __builtin_amdgcn_mfma_f32_16x16x32_bf16(pa0[0], ones, lacc[0], 0, 0, 0);
        lacc[0] = __builtin_amdgcn_mfma_f32_16x16x32_bf16(pa0[1], ones, lacc[0], 0, 0, 0);
        lacc[1] = __builtin_amdgcn_mfma_f32_16x16x32_bf16(pa1[0], ones, lacc[1], 0, 0, 0);
        lacc[1] = __builtin_amdgcn_mfma_f32_16x16x32_bf16(pa1[1], ones, lacc[1], 0, 0, 0);
#pragma unroll
        for (int kk = 0; kk < 2; ++kk) {
#pragma unroll
            for (int dt = 0; dt < 8; ++dt) {
                const int row = dt * 16 + l15;
                const int pcg = (kk * 4 + quad) ^ (l15 & 7);
                bf16x8 bv = *(const bf16x8*)(vb + row * 64 + pcg * 8);
                o[0][dt] = __builtin_amdgcn_mfma_f32_16x16x32_bf16(kk ? pa0[1] : pa0[0], bv, o[0][dt], 0, 0, 0);
                o[1][dt] = __builtin_amdgcn_mfma_f32_16x16x32_bf16(kk ? pa1[1] : pa1[0], bv, o[1][dt], 0, 0, 0);
            }
        }
        __builtin_amdgcn_s_setprio(0);
    }
#undef STAGE_K
#undef STAGE_V

#pragma unroll
    for (int hh = 0; hh < 2; ++hh)
#pragma unroll
        for (int r = 0; r < 4; ++r) {
            const float inv = 1.0f / lacc[hh][r];
            const size_t row = qw + hh * 16 + quad * 4 + r;
            bf16* op = AO + row * 3072 + h * 128 + l15;
#pragma unroll
            for (int dt = 0; dt < 8; ++dt) op[dt * 16] = (bf16)(o[hh][dt][r] * inv);
        }
}

// ---------------------------------------------------------------------------
extern "C" void kernel_launch(void* const* d_in, const int* in_sizes, int n_in,
                              void* d_out, int out_size, void* d_ws, size_t ws_size,
                              hipStream_t stream)
{
    (void)in_sizes; (void)n_in; (void)out_size;

    const float* x      = (const float*)d_in[0];
    const float* pe     = (const float*)d_in[1];
    const float* w_qkv  = (const float*)d_in[2];
    const float* w_proj = (const float*)d_in[3];
    const float* b_proj = (const float*)d_in[4];
    const float* q_s    = (const float*)d_in[5];
    const float* k_s    = (const float*)d_in[6];
    float* out = (float*)d_out;

    const size_t NEED_BIG = ((size_t)6291456 + 28311552 + 18874368 + 6291456) * 2; // 119.5 MB

    if (ws_size >= NEED_BIG) {
        // single-launch QKV path
        bf16* xb  = (bf16*)d_ws;                  //  6291456  x bf16
        bf16* wb  = xb + (size_t)6291456;         // 28311552  w_qkv bf16
        bf16* qkv = wb + (size_t)28311552;        // 18874368  [2048][9216]
        bf16* Vt  = qkv + (size_t)18874368;       //  6291456  [24][128][2048]
        bf16* Qh  = xb;                           // alias after GEMM
        bf16* Kh  = wb;                           // alias after GEMM
        bf16* wpb = qkv;                          // alias after rearrange
        bf16* AO  = qkv + (size_t)9437184;

        f32_to_bf16<<<dim3(3072),  256, 0, stream>>>(x,     xb, 786432);
        f32_to_bf16<<<dim3(13824), 256, 0, stream>>>(w_qkv, wb, 3538944);
        // 128x192 GEMM @ 2 blocks/CU: grid 48x16 = 768 blocks = exactly 3/CU
        gemm128_bt<0, bf16><<<dim3(48, 16), 512, 0, stream>>>(xb, wb, nullptr, qkv, 3072, 9216);
        qk_rope_rearrange<<<dim3(12288), 256, 0, stream>>>(qkv, pe, q_s, k_s, Qh, Kh, Vt);
        f32_to_bf16<<<dim3(4608), 256, 0, stream>>>(w_proj, wpb, 1179648);
        // flash v6: 128 q/block -> grid 16x24 = 384 blocks @ 2/CU
        flash_attn<<<dim3(16, 24), 256, 0, stream>>>(Qh, Kh, Vt, AO);
        // 64x192 proj GEMM @ 2 blocks/CU: grid 16x32 = 512 blocks = exactly 2/CU
        gemm64_bt<1, float><<<dim3(16, 32), 512, 0, stream>>>(AO, wpb, b_proj, out, 3072, 3072);
    } else {
        // chunked fallback (78.6 MB peak)
        bf16* xb  = (bf16*)d_ws;
        bf16* wb  = xb + (size_t)6291456;
        bf16* qkv = wb + (size_t)9437184;
        bf16* Vt  = qkv + (size_t)18874368;
        bf16* Qh  = xb;
        bf16* Kh  = wb;
        bf16* wpb = qkv;
        bf16* AO  = qkv + (size_t)9437184;

        f32_to_bf16<<<dim3(3072), 256, 0, stream>>>(x, xb, 786432);
        for (int c = 0; c < 3; ++c) {
            f32_to_bf16<<<dim3(4608), 256, 0, stream>>>(w_qkv + (size_t)c * 9437184, wb, 1179648);
            gemm_bt<0, bf16><<<dim3(24, 16), 256, 0, stream>>>(xb, wb, nullptr, qkv + c * 3072, 3072, 9216);
        }
        qk_rope_rearrange<<<dim3(12288), 256, 0, stream>>>(qkv, pe, q_s, k_s, Qh, Kh, Vt);
        f32_to_bf16<<<dim3(4608), 256, 0, stream>>>(w_proj, wpb, 1179648);
        flash_attn<<<dim3(16, 24), 256, 0, stream>>>(Qh, Kh, Vt, AO);
        gemm64_bt<1, float><<<dim3(16, 32), 512, 0, stream>>>(AO, wpb, b_proj, out, 3072, 3072);
    }
}